// Round 1
// baseline (4123.033 us; speedup 1.0000x reference)
//
#include <hip/hip_runtime.h>

typedef unsigned short u16;
typedef unsigned int u32;

#define TT 16

// ---------------------------------------------------------------------------
// LIF scan (soft reset, THETA=1.0) over the 16 per-timestep inputs held in acc.
// Returns packed spike bitmask (bit t = spike at timestep t).
// All math in f64: spike-decision margins (~1e-8 min over ~1.7e8 decisions)
// are below f32 noise but far above f64 noise.
// ---------------------------------------------------------------------------
__device__ __forceinline__ u32 scan_spike(const double* acc) {
  double u = 0.0;
  u32 m = 0;
#pragma unroll
  for (int t = 0; t < TT; ++t) {
    u += acc[t];
    if (u >= 1.0) { m |= (1u << t); u -= 1.0; }
  }
  return m;
}

// ---------------------------------------------------------------------------
// Layer 1: conv3x3 pad1, Cin=1 (continuous f32 input, T innermost) + spike.
// x: [128,1,28,28,16] f32, w: [32,1,3,3], out: packed u16 [128,32,28,28]
// ---------------------------------------------------------------------------
__global__ __launch_bounds__(256) void conv1_spike(
    const float* __restrict__ x, const float* __restrict__ w,
    const float* __restrict__ b, u16* __restrict__ out) {
  int idx = blockIdx.x * 256 + threadIdx.x;
  const int total = 128 * 32 * 28 * 28;
  if (idx >= total) return;
  int xx = idx % 28; int t1 = idx / 28;
  int yy = t1 % 28;  int t2 = t1 / 28;
  int o  = t2 % 32;  int n  = t2 / 32;

  double acc[TT];
  double bv = (double)b[o];
#pragma unroll
  for (int t = 0; t < TT; ++t) acc[t] = bv;

#pragma unroll
  for (int dy = 0; dy < 3; ++dy) {
    int yi = yy + dy - 1;
    if ((unsigned)yi >= 28u) continue;
#pragma unroll
    for (int dx = 0; dx < 3; ++dx) {
      int xi = xx + dx - 1;
      if ((unsigned)xi >= 28u) continue;
      double wv = (double)w[o * 9 + dy * 3 + dx];
      const float* xp = x + ((size_t)(n * 28 + yi) * 28 + xi) * TT;
#pragma unroll
      for (int t = 0; t < TT; ++t) acc[t] += wv * (double)xp[t];
    }
  }
  out[idx] = (u16)scan_spike(acc);
}

// ---------------------------------------------------------------------------
// Generic conv3x3 pad1 on packed binary input + optional residual + spike.
// in: [N,CIN,H,W] packed u16; w: [Cout,CIN,3,3] f32; res: same shape as out
// ---------------------------------------------------------------------------
template <int CIN>
__global__ __launch_bounds__(256) void conv3x3_spike(
    const u16* __restrict__ in, const float* __restrict__ w,
    const float* __restrict__ b, const u16* __restrict__ res,
    u16* __restrict__ out, int N, int Cout, int H, int W) {
  int idx = blockIdx.x * 256 + threadIdx.x;
  int total = N * Cout * H * W;
  if (idx >= total) return;
  int xx = idx % W; int t1 = idx / W;
  int yy = t1 % H;  int t2 = t1 / H;
  int o  = t2 % Cout; int n = t2 / Cout;

  double acc[TT];
  double bv = (double)b[o];
#pragma unroll
  for (int t = 0; t < TT; ++t) acc[t] = bv;

  const u16* inn = in + (size_t)n * CIN * H * W;
  const float* wo = w + (size_t)o * CIN * 9;

  for (int c = 0; c < CIN; ++c) {
    const u16* inc = inn + c * H * W;
    const float* wc = wo + c * 9;
#pragma unroll
    for (int dy = 0; dy < 3; ++dy) {
      int yi = yy + dy - 1;
      if ((unsigned)yi >= (unsigned)H) continue;
      const u16* row = inc + yi * W;
#pragma unroll
      for (int dx = 0; dx < 3; ++dx) {
        int xi = xx + dx - 1;
        if ((unsigned)xi >= (unsigned)W) continue;
        double wv = (double)wc[dy * 3 + dx];
        u32 m = row[xi];
#pragma unroll
        for (int t = 0; t < TT; ++t) acc[t] += ((m >> t) & 1u) ? wv : 0.0;
      }
    }
  }
  if (res) {
    u32 m = res[idx];
#pragma unroll
    for (int t = 0; t < TT; ++t) acc[t] += ((m >> t) & 1u) ? 1.0 : 0.0;
  }
  out[idx] = (u16)scan_spike(acc);
}

// ---------------------------------------------------------------------------
// 2x2 average pool on packed binary input + spike. in: [128,32,28,28] ->
// out: [128,32,14,14]
// ---------------------------------------------------------------------------
__global__ __launch_bounds__(256) void pool_spike(
    const u16* __restrict__ in, u16* __restrict__ out) {
  int idx = blockIdx.x * 256 + threadIdx.x;
  const int total = 128 * 32 * 14 * 14;
  if (idx >= total) return;
  int xx = idx % 14; int t1 = idx / 14;
  int yy = t1 % 14;  int t2 = t1 / 14;
  int c  = t2 % 32;  int n  = t2 / 32;

  const u16* base = in + ((size_t)(n * 32 + c) * 28 + yy * 2) * 28 + xx * 2;
  u32 m00 = base[0], m01 = base[1], m10 = base[28], m11 = base[29];

  double acc[TT];
#pragma unroll
  for (int t = 0; t < TT; ++t) {
    u32 s = ((m00 >> t) & 1u) + ((m01 >> t) & 1u) + ((m10 >> t) & 1u) +
            ((m11 >> t) & 1u);
    acc[t] = 0.25 * (double)s;  // k/4: exact in f64
  }
  out[idx] = (u16)scan_spike(acc);
}

// ---------------------------------------------------------------------------
// Generic conv1x1 on packed binary input + optional residual + spike.
// ---------------------------------------------------------------------------
template <int CIN>
__global__ __launch_bounds__(256) void conv1x1_spike(
    const u16* __restrict__ in, const float* __restrict__ w,
    const float* __restrict__ b, const u16* __restrict__ res,
    u16* __restrict__ out, int N, int Cout, int HW) {
  int idx = blockIdx.x * 256 + threadIdx.x;
  int total = N * Cout * HW;
  if (idx >= total) return;
  int p = idx % HW; int t1 = idx / HW;
  int o = t1 % Cout; int n = t1 / Cout;

  double acc[TT];
  double bv = (double)b[o];
#pragma unroll
  for (int t = 0; t < TT; ++t) acc[t] = bv;

  const u16* inp = in + (size_t)n * CIN * HW + p;
  const float* wo = w + (size_t)o * CIN;
#pragma unroll 4
  for (int c = 0; c < CIN; ++c) {
    u32 m = inp[c * HW];
    double wv = (double)wo[c];
#pragma unroll
    for (int t = 0; t < TT; ++t) acc[t] += ((m >> t) & 1u) ? wv : 0.0;
  }
  if (res) {
    u32 m = res[idx];
#pragma unroll
    for (int t = 0; t < TT; ++t) acc[t] += ((m >> t) & 1u) ? 1.0 : 0.0;
  }
  out[idx] = (u16)scan_spike(acc);
}

// ---------------------------------------------------------------------------
// Dense 6272 -> 128 + spike. One wave (64 lanes) per (n,o); lanes partial-sum
// strided features, butterfly-reduce in f64, lane 0 scans.
// in: [128][6272] packed u16 (f index = (c*14+h)*14+w, matches reshape order)
// ---------------------------------------------------------------------------
__global__ __launch_bounds__(64) void dense1_spike(
    const u16* __restrict__ in, const float* __restrict__ w,
    const float* __restrict__ b, u16* __restrict__ out) {
  int bid = blockIdx.x;  // 0..16383
  int o = bid & 127;
  int n = bid >> 7;
  int lane = threadIdx.x;

  double acc[TT];
#pragma unroll
  for (int t = 0; t < TT; ++t) acc[t] = 0.0;

  const u16* inn = in + (size_t)n * 6272;
  const float* wo = w + (size_t)o * 6272;
  for (int f = lane; f < 6272; f += 64) {  // 6272/64 = 98 iters, coalesced
    u32 m = inn[f];
    double wv = (double)wo[f];
#pragma unroll
    for (int t = 0; t < TT; ++t) acc[t] += ((m >> t) & 1u) ? wv : 0.0;
  }
#pragma unroll
  for (int t = 0; t < TT; ++t) {
#pragma unroll
    for (int off = 32; off > 0; off >>= 1) acc[t] += __shfl_down(acc[t], off);
  }
  if (lane == 0) {
    double bv = (double)b[o];
    double u = 0.0;
    u32 mo = 0;
#pragma unroll
    for (int t = 0; t < TT; ++t) {
      u += acc[t] + bv;  // bias added every timestep
      if (u >= 1.0) { mo |= (1u << t); u -= 1.0; }
    }
    out[n * 128 + o] = (u16)mo;
  }
}

// ---------------------------------------------------------------------------
// Dense 128 -> 10 + spike + firing-rate output. out: [128,10] f32
// ---------------------------------------------------------------------------
__global__ __launch_bounds__(64) void dense2_out(
    const u16* __restrict__ in, const float* __restrict__ w,
    const float* __restrict__ b, float* __restrict__ out) {
  int idx = blockIdx.x * 64 + threadIdx.x;
  if (idx >= 1280) return;
  int o = idx % 10;
  int n = idx / 10;

  double acc[TT];
  double bv = (double)b[o];
#pragma unroll
  for (int t = 0; t < TT; ++t) acc[t] = bv;

  const u16* inn = in + (size_t)n * 128;
  const float* wo = w + (size_t)o * 128;
  for (int f = 0; f < 128; ++f) {
    u32 m = inn[f];
    double wv = (double)wo[f];
#pragma unroll
    for (int t = 0; t < TT; ++t) acc[t] += ((m >> t) & 1u) ? wv : 0.0;
  }
  u32 mo = scan_spike(acc);
  out[idx] = (float)__popc(mo) * 0.0625f;  // count / 16
}

// ---------------------------------------------------------------------------
extern "C" void kernel_launch(void* const* d_in, const int* in_sizes, int n_in,
                              void* d_out, int out_size, void* d_ws,
                              size_t ws_size, hipStream_t stream) {
  const float* x   = (const float*)d_in[0];
  const float* w1  = (const float*)d_in[1];
  const float* b1  = (const float*)d_in[2];
  const float* w2  = (const float*)d_in[3];
  const float* b2  = (const float*)d_in[4];
  const float* w3  = (const float*)d_in[5];
  const float* b3  = (const float*)d_in[6];
  const float* w4  = (const float*)d_in[7];
  const float* b4  = (const float*)d_in[8];
  const float* w5  = (const float*)d_in[9];
  const float* b5  = (const float*)d_in[10];
  const float* w6  = (const float*)d_in[11];
  const float* b6  = (const float*)d_in[12];
  const float* wf1 = (const float*)d_in[13];
  const float* bf1 = (const float*)d_in[14];
  const float* wf2 = (const float*)d_in[15];
  const float* bf2 = (const float*)d_in[16];
  float* out = (float*)d_out;

  // Workspace layout (packed u16 spike masks), ~24.1 MB total
  u16* s1 = (u16*)d_ws;            // [128,32,28,28] = 3211264
  u16* s2 = s1 + 3211264;          // [128,32,28,28]
  u16* s3 = s2 + 3211264;          // [128,32,28,28]
  u16* s4 = s3 + 3211264;          // [128,32,14,14] = 802816
  u16* s5 = s4 + 802816;           // [128,16,14,14] = 401408
  u16* s6 = s5 + 401408;           // [128,16,14,14]
  u16* s7 = s6 + 401408;           // [128,32,14,14] = 802816
  u16* s8 = s7 + 802816;           // [128,128] = 16384

  // L1: conv3x3 1->32 pad1 + spike
  conv1_spike<<<(3211264 + 255) / 256, 256, 0, stream>>>(x, w1, b1, s1);
  // L2: conv3x3 32->32 pad1 + spike
  conv3x3_spike<32><<<(3211264 + 255) / 256, 256, 0, stream>>>(
      s1, w2, b2, nullptr, s2, 128, 32, 28, 28);
  // L3: conv3x3 32->32 pad1 + residual(s1) + spike
  conv3x3_spike<32><<<(3211264 + 255) / 256, 256, 0, stream>>>(
      s2, w3, b3, s1, s3, 128, 32, 28, 28);
  // L4: avgpool2 + spike
  pool_spike<<<(802816 + 255) / 256, 256, 0, stream>>>(s3, s4);
  // L5: conv1x1 32->16 + spike
  conv1x1_spike<32><<<(401408 + 255) / 256, 256, 0, stream>>>(
      s4, w4, b4, nullptr, s5, 128, 16, 196);
  // L6: conv3x3 16->16 pad1 + spike
  conv3x3_spike<16><<<(401408 + 255) / 256, 256, 0, stream>>>(
      s5, w5, b5, nullptr, s6, 128, 16, 14, 14);
  // L7: conv1x1 16->32 + residual(s4) + spike
  conv1x1_spike<16><<<(802816 + 255) / 256, 256, 0, stream>>>(
      s6, w6, b6, s4, s7, 128, 32, 196);
  // L8: dense 6272->128 + spike (one wave per (n,o))
  dense1_spike<<<16384, 64, 0, stream>>>(s7, wf1, bf1, s8);
  // L9: dense 128->10 + spike + rate
  dense2_out<<<(1280 + 63) / 64, 64, 0, stream>>>(s8, wf2, bf2, out);
}

// Round 2
// 2061.783 us; speedup vs baseline: 1.9997x; 1.9997x over previous
//
#include <hip/hip_runtime.h>

typedef unsigned short u16;
typedef unsigned int u32;

#define TT 16

// ---------------------------------------------------------------------------
// LIF scan (soft reset, THETA=1.0). All math f64: spike-decision margins
// (~1e-9 min over ~1.7e8 decisions) are below f32 noise, far above f64 noise.
// ---------------------------------------------------------------------------
__device__ __forceinline__ u32 scan_spike(const double* acc) {
  double u = 0.0;
  u32 m = 0;
#pragma unroll
  for (int t = 0; t < TT; ++t) {
    u += acc[t];
    if (u >= 1.0) { m |= (1u << t); u -= 1.0; }
  }
  return m;
}

// ---------------------------------------------------------------------------
// Layer 1: conv3x3 pad1, Cin=1 (continuous f32 input, T innermost) + spike.
// ---------------------------------------------------------------------------
__global__ __launch_bounds__(256) void conv1_spike(
    const float* __restrict__ x, const float* __restrict__ w,
    const float* __restrict__ b, u16* __restrict__ out) {
  int idx = blockIdx.x * 256 + threadIdx.x;
  const int total = 128 * 32 * 28 * 28;
  if (idx >= total) return;
  int xx = idx % 28; int t1 = idx / 28;
  int yy = t1 % 28;  int t2 = t1 / 28;
  int o  = t2 % 32;  int n  = t2 / 32;

  double acc[TT];
  double bv = (double)b[o];
#pragma unroll
  for (int t = 0; t < TT; ++t) acc[t] = bv;

#pragma unroll
  for (int dy = 0; dy < 3; ++dy) {
    int yi = yy + dy - 1;
    if ((unsigned)yi >= 28u) continue;
#pragma unroll
    for (int dx = 0; dx < 3; ++dx) {
      int xi = xx + dx - 1;
      if ((unsigned)xi >= 28u) continue;
      double wv = (double)w[o * 9 + dy * 3 + dx];
      const float* xp = x + ((size_t)(n * 28 + yi) * 28 + xi) * TT;
#pragma unroll
      for (int t = 0; t < TT; ++t) acc[t] += wv * (double)xp[t];
    }
  }
  out[idx] = (u16)scan_spike(acc);
}

// ---------------------------------------------------------------------------
// FMA-formulated conv3x3 pad1 on packed binary input + optional residual +
// spike. One wave = one group of 4 output channels over a 16x4 pixel tile.
// acc += bit ? w : 0  ==  acc = fma(w/2, bit ? 2.0 : 0.0, acc)  (bit-identical:
// w/2 exact, (w/2)*2.0 exact, single fma rounding == add rounding; 2.0 hi-word
// is bit<<30). Bit expansion (2 insts) amortized over 4 ocs (4 v_fma_f64).
// Masks staged in LDS [c][6][18] (u16 2-way bank aliasing = free).
// ---------------------------------------------------------------------------
template <int CIN, int COUT, int H, int W>
__global__ __launch_bounds__((COUT / 4) * 64) void conv3x3_fma(
    const u16* __restrict__ in, const float* __restrict__ w,
    const float* __restrict__ b, const u16* __restrict__ res,
    u16* __restrict__ out) {
  constexpr int TX = 16, TY = 4;
  constexpr int TILESX = (W + TX - 1) / TX;
  constexpr int TILESY = (H + TY - 1) / TY;
  constexpr int HALO = 6 * (TX + 2);   // per-channel halo elems
  constexpr int BLOCK = (COUT / 4) * 64;
  __shared__ u16 lds[CIN][6][TX + 2];

  int blk = blockIdx.x;
  int tx = blk % TILESX; int t1 = blk / TILESX;
  int ty = t1 % TILESY;  int n  = t1 / TILESY;
  int x0 = tx * TX, y0 = ty * TY;

  int tid = threadIdx.x;

  // ---- stage input masks (with zero halo) into LDS, coalesced in cc ----
  const u16* inn = in + (size_t)n * CIN * H * W;
  for (int idx = tid; idx < CIN * HALO; idx += BLOCK) {
    int c = idx / HALO; int rem = idx % HALO;
    int r = rem / (TX + 2); int cc = rem % (TX + 2);
    int gy = y0 - 1 + r, gx = x0 - 1 + cc;
    u16 v = 0;
    if ((unsigned)gy < (unsigned)H && (unsigned)gx < (unsigned)W)
      v = inn[(size_t)c * H * W + gy * W + gx];
    lds[c][r][cc] = v;
  }
  __syncthreads();

  int lane = tid & 63;
  int og = __builtin_amdgcn_readfirstlane(tid >> 6);  // wave-uniform ocgroup
  int oc0 = og * 4;
  int px = lane & 15, py = lane >> 4;  // 16x4 = 64 lanes exactly

  double acc[4][TT];
#pragma unroll
  for (int j = 0; j < 4; ++j) {
    double bv = (double)b[oc0 + j];
#pragma unroll
    for (int t = 0; t < TT; ++t) acc[j][t] = bv;
  }

  for (int c = 0; c < CIN; ++c) {
    const float* wc = w + ((size_t)oc0 * CIN + c) * 9;  // oc stride = CIN*9
#pragma unroll
    for (int ky = 0; ky < 3; ++ky) {
#pragma unroll
      for (int kx = 0; kx < 3; ++kx) {
        u32 m = lds[c][py + ky][px + kx];
        int ko = ky * 3 + kx;
        double wh0 = 0.5 * (double)wc[ko];              // exact
        double wh1 = 0.5 * (double)wc[CIN * 9 + ko];
        double wh2 = 0.5 * (double)wc[2 * CIN * 9 + ko];
        double wh3 = 0.5 * (double)wc[3 * CIN * 9 + ko];
#pragma unroll
        for (int t = 0; t < TT; ++t) {
          u32 hi = (m << (30 - t)) & 0x40000000u;       // 2.0 or 0.0 hi-word
          double bf = __hiloint2double((int)hi, 0);
          acc[0][t] = fma(wh0, bf, acc[0][t]);
          acc[1][t] = fma(wh1, bf, acc[1][t]);
          acc[2][t] = fma(wh2, bf, acc[2][t]);
          acc[3][t] = fma(wh3, bf, acc[3][t]);
        }
      }
    }
  }

  int gx = x0 + px, gy = y0 + py;
  if (gx < W && gy < H) {
#pragma unroll
    for (int j = 0; j < 4; ++j) {
      size_t oidx = ((size_t)(n * COUT + oc0 + j) * H + gy) * W + gx;
      double u = 0.0;
      u32 mo = 0;
      if (res) {
        u32 rm = res[oidx];
#pragma unroll
        for (int t = 0; t < TT; ++t) {
          double a = acc[j][t] + (((rm >> t) & 1u) ? 1.0 : 0.0);
          u += a;
          if (u >= 1.0) { mo |= (1u << t); u -= 1.0; }
        }
      } else {
#pragma unroll
        for (int t = 0; t < TT; ++t) {
          u += acc[j][t];
          if (u >= 1.0) { mo |= (1u << t); u -= 1.0; }
        }
      }
      out[oidx] = (u16)mo;
    }
  }
}

// ---------------------------------------------------------------------------
// 2x2 average pool on packed binary input + spike.
// ---------------------------------------------------------------------------
__global__ __launch_bounds__(256) void pool_spike(
    const u16* __restrict__ in, u16* __restrict__ out) {
  int idx = blockIdx.x * 256 + threadIdx.x;
  const int total = 128 * 32 * 14 * 14;
  if (idx >= total) return;
  int xx = idx % 14; int t1 = idx / 14;
  int yy = t1 % 14;  int t2 = t1 / 14;
  int c  = t2 % 32;  int n  = t2 / 32;

  const u16* base = in + ((size_t)(n * 32 + c) * 28 + yy * 2) * 28 + xx * 2;
  u32 m00 = base[0], m01 = base[1], m10 = base[28], m11 = base[29];

  double acc[TT];
#pragma unroll
  for (int t = 0; t < TT; ++t) {
    u32 s = ((m00 >> t) & 1u) + ((m01 >> t) & 1u) + ((m10 >> t) & 1u) +
            ((m11 >> t) & 1u);
    acc[t] = 0.25 * (double)s;  // k/4: exact in f64
  }
  out[idx] = (u16)scan_spike(acc);
}

// ---------------------------------------------------------------------------
// Generic conv1x1 on packed binary input + optional residual + spike.
// ---------------------------------------------------------------------------
template <int CIN>
__global__ __launch_bounds__(256) void conv1x1_spike(
    const u16* __restrict__ in, const float* __restrict__ w,
    const float* __restrict__ b, const u16* __restrict__ res,
    u16* __restrict__ out, int N, int Cout, int HW) {
  int idx = blockIdx.x * 256 + threadIdx.x;
  int total = N * Cout * HW;
  if (idx >= total) return;
  int p = idx % HW; int t1 = idx / HW;
  int o = t1 % Cout; int n = t1 / Cout;

  double acc[TT];
  double bv = (double)b[o];
#pragma unroll
  for (int t = 0; t < TT; ++t) acc[t] = bv;

  const u16* inp = in + (size_t)n * CIN * HW + p;
  const float* wo = w + (size_t)o * CIN;
#pragma unroll 4
  for (int c = 0; c < CIN; ++c) {
    u32 m = inp[c * HW];
    double wh = 0.5 * (double)wo[c];
#pragma unroll
    for (int t = 0; t < TT; ++t) {
      u32 hi = (m << (30 - t)) & 0x40000000u;
      acc[t] = fma(wh, __hiloint2double((int)hi, 0), acc[t]);
    }
  }
  if (res) {
    u32 m = res[idx];
#pragma unroll
    for (int t = 0; t < TT; ++t) acc[t] += ((m >> t) & 1u) ? 1.0 : 0.0;
  }
  out[idx] = (u16)scan_spike(acc);
}

// ---------------------------------------------------------------------------
// Dense 6272 -> 128 + spike. One wave per (n,o).
// ---------------------------------------------------------------------------
__global__ __launch_bounds__(64) void dense1_spike(
    const u16* __restrict__ in, const float* __restrict__ w,
    const float* __restrict__ b, u16* __restrict__ out) {
  int bid = blockIdx.x;
  int o = bid & 127;
  int n = bid >> 7;
  int lane = threadIdx.x;

  double acc[TT];
#pragma unroll
  for (int t = 0; t < TT; ++t) acc[t] = 0.0;

  const u16* inn = in + (size_t)n * 6272;
  const float* wo = w + (size_t)o * 6272;
  for (int f = lane; f < 6272; f += 64) {
    u32 m = inn[f];
    double wh = 0.5 * (double)wo[f];
#pragma unroll
    for (int t = 0; t < TT; ++t) {
      u32 hi = (m << (30 - t)) & 0x40000000u;
      acc[t] = fma(wh, __hiloint2double((int)hi, 0), acc[t]);
    }
  }
#pragma unroll
  for (int t = 0; t < TT; ++t) {
#pragma unroll
    for (int off = 32; off > 0; off >>= 1) acc[t] += __shfl_down(acc[t], off);
  }
  if (lane == 0) {
    double bv = (double)b[o];
    double u = 0.0;
    u32 mo = 0;
#pragma unroll
    for (int t = 0; t < TT; ++t) {
      u += acc[t] + bv;
      if (u >= 1.0) { mo |= (1u << t); u -= 1.0; }
    }
    out[n * 128 + o] = (u16)mo;
  }
}

// ---------------------------------------------------------------------------
// Dense 128 -> 10 + spike + firing-rate output. out: [128,10] f32
// ---------------------------------------------------------------------------
__global__ __launch_bounds__(64) void dense2_out(
    const u16* __restrict__ in, const float* __restrict__ w,
    const float* __restrict__ b, float* __restrict__ out) {
  int idx = blockIdx.x * 64 + threadIdx.x;
  if (idx >= 1280) return;
  int o = idx % 10;
  int n = idx / 10;

  double acc[TT];
  double bv = (double)b[o];
#pragma unroll
  for (int t = 0; t < TT; ++t) acc[t] = bv;

  const u16* inn = in + (size_t)n * 128;
  const float* wo = w + (size_t)o * 128;
  for (int f = 0; f < 128; ++f) {
    u32 m = inn[f];
    double wv = (double)wo[f];
#pragma unroll
    for (int t = 0; t < TT; ++t) acc[t] += ((m >> t) & 1u) ? wv : 0.0;
  }
  u32 mo = scan_spike(acc);
  out[idx] = (float)__popc(mo) * 0.0625f;
}

// ---------------------------------------------------------------------------
extern "C" void kernel_launch(void* const* d_in, const int* in_sizes, int n_in,
                              void* d_out, int out_size, void* d_ws,
                              size_t ws_size, hipStream_t stream) {
  const float* x   = (const float*)d_in[0];
  const float* w1  = (const float*)d_in[1];
  const float* b1  = (const float*)d_in[2];
  const float* w2  = (const float*)d_in[3];
  const float* b2  = (const float*)d_in[4];
  const float* w3  = (const float*)d_in[5];
  const float* b3  = (const float*)d_in[6];
  const float* w4  = (const float*)d_in[7];
  const float* b4  = (const float*)d_in[8];
  const float* w5  = (const float*)d_in[9];
  const float* b5  = (const float*)d_in[10];
  const float* w6  = (const float*)d_in[11];
  const float* b6  = (const float*)d_in[12];
  const float* wf1 = (const float*)d_in[13];
  const float* bf1 = (const float*)d_in[14];
  const float* wf2 = (const float*)d_in[15];
  const float* bf2 = (const float*)d_in[16];
  float* out = (float*)d_out;

  // Workspace layout (packed u16 spike masks), ~24.1 MB total
  u16* s1 = (u16*)d_ws;            // [128,32,28,28]
  u16* s2 = s1 + 3211264;
  u16* s3 = s2 + 3211264;
  u16* s4 = s3 + 3211264;          // [128,32,14,14]
  u16* s5 = s4 + 802816;           // [128,16,14,14]
  u16* s6 = s5 + 401408;
  u16* s7 = s6 + 401408;           // [128,32,14,14]
  u16* s8 = s7 + 802816;           // [128,128]

  // L1: conv3x3 1->32 pad1 + spike
  conv1_spike<<<(3211264 + 255) / 256, 256, 0, stream>>>(x, w1, b1, s1);
  // L2: conv3x3 32->32 pad1 + spike  (tiles: 2x in x, 7 in y, 128 n)
  conv3x3_fma<32, 32, 28, 28><<<128 * 7 * 2, 512, 0, stream>>>(
      s1, w2, b2, nullptr, s2);
  // L3: conv3x3 32->32 pad1 + residual(s1) + spike
  conv3x3_fma<32, 32, 28, 28><<<128 * 7 * 2, 512, 0, stream>>>(
      s2, w3, b3, s1, s3);
  // L4: avgpool2 + spike
  pool_spike<<<(802816 + 255) / 256, 256, 0, stream>>>(s3, s4);
  // L5: conv1x1 32->16 + spike
  conv1x1_spike<32><<<(401408 + 255) / 256, 256, 0, stream>>>(
      s4, w4, b4, nullptr, s5, 128, 16, 196);
  // L6: conv3x3 16->16 pad1 + spike  (tiles: 1x in x, 4 in y)
  conv3x3_fma<16, 16, 14, 14><<<128 * 4 * 1, 256, 0, stream>>>(
      s5, w5, b5, nullptr, s6);
  // L7: conv1x1 16->32 + residual(s4) + spike
  conv1x1_spike<16><<<(802816 + 255) / 256, 256, 0, stream>>>(
      s6, w6, b6, s4, s7, 128, 32, 196);
  // L8: dense 6272->128 + spike
  dense1_spike<<<16384, 64, 0, stream>>>(s7, wf1, bf1, s8);
  // L9: dense 128->10 + spike + rate
  dense2_out<<<(1280 + 63) / 64, 64, 0, stream>>>(s8, wf2, bf2, out);
}

// Round 3
// 1148.809 us; speedup vs baseline: 3.5890x; 1.7947x over previous
//
#include <hip/hip_runtime.h>

typedef unsigned short u16;
typedef unsigned int u32;
typedef __attribute__((ext_vector_type(4))) int i32x4;

#define TT 16

// ---------------------------------------------------------------------------
// LIF scan (soft reset, THETA=1.0). All math f64: spike-decision margins
// (~1e-8 min over ~1e8 decisions) are below f32 noise, far above f64 noise.
// R2 established order-freedom: absmax=0.0 with our own summation order.
// ---------------------------------------------------------------------------
__device__ __forceinline__ u32 scan_spike(const double* acc) {
  double u = 0.0;
  u32 m = 0;
#pragma unroll
  for (int t = 0; t < TT; ++t) {
    u += acc[t];
    if (u >= 1.0) { m |= (1u << t); u -= 1.0; }
  }
  return m;
}

// ---------------------------------------------------------------------------
// Layer 1: conv3x3 pad1, Cin=1 (continuous f32 input, T innermost) + spike.
// ---------------------------------------------------------------------------
__global__ __launch_bounds__(256) void conv1_spike(
    const float* __restrict__ x, const float* __restrict__ w,
    const float* __restrict__ b, u16* __restrict__ out) {
  int idx = blockIdx.x * 256 + threadIdx.x;
  const int total = 128 * 32 * 28 * 28;
  if (idx >= total) return;
  int xx = idx % 28; int t1 = idx / 28;
  int yy = t1 % 28;  int t2 = t1 / 28;
  int o  = t2 % 32;  int n  = t2 / 32;

  double acc[TT];
  double bv = (double)b[o];
#pragma unroll
  for (int t = 0; t < TT; ++t) acc[t] = bv;

#pragma unroll
  for (int dy = 0; dy < 3; ++dy) {
    int yi = yy + dy - 1;
    if ((unsigned)yi >= 28u) continue;
#pragma unroll
    for (int dx = 0; dx < 3; ++dx) {
      int xi = xx + dx - 1;
      if ((unsigned)xi >= 28u) continue;
      double wv = (double)w[o * 9 + dy * 3 + dx];
      const float* xp = x + ((size_t)(n * 28 + yi) * 28 + xi) * TT;
#pragma unroll
      for (int t = 0; t < TT; ++t) acc[t] += wv * (double)xp[t];
    }
  }
  out[idx] = (u16)scan_spike(acc);
}

// ---------------------------------------------------------------------------
// Digit prep: w[32][32][3][3] f32 -> 6 signed base-256 digit planes, i8.
// X = rint(w * 2^45), |X| < 2^47 (|w| < 4 guaranteed: sigma=0.059).
// w == sum_p d_p * 2^(8p-45) exactly for |w| >= 2^-22; else err <= 2^-46.
// A layout: [plane 6][oc 32][k' 320] with k' = tap*32 + c  (taps 9 real + 1
// zero-pad tap so K' = 320 = 5 * 64 MFMA chunks).
// ---------------------------------------------------------------------------
__global__ void prep_digits(const float* __restrict__ w,
                            signed char* __restrict__ A) {
  int oc = blockIdx.x;    // 32
  int c = threadIdx.x;    // 32
  for (int tap = 0; tap < 10; ++tap) {
    long long X = 0;
    if (tap < 9) {
      double xv = ldexp((double)w[(oc * 32 + c) * 9 + tap], 45);
      X = (long long)rint(xv);
    }
    for (int p = 0; p < 6; ++p) {
      int d = (int)((X + 128) & 255) - 128;
      A[(p * 32 + oc) * 320 + tap * 32 + c] = (signed char)d;
      X = (X - (long long)d) >> 8;
    }
  }
}

// ---------------------------------------------------------------------------
// conv3x3 32->32 pad1 on packed binary input via exact i8 MFMA + spike.
// Block = 256 thr (4 waves) = one (n, y-row, 8-px x-tile). Columns of the
// GEMM are (px, t): subtile s (16 cols) = pixel px=s across 16 timesteps.
// K' = 320 (k = tap*32 + c). Per wave: 2 subtiles x 2 oc-halves x 6 planes x
// 5 k-chunks of v_mfma_i32_16x16x64_i8 (exact), recombined in f64:
//   conv = bias + sum_p (double)acc_p * 2^(8p-45).
// S built in LDS [col][k] via 32x32 bit-transpose (5 shfl_xor stages) +
// nibble->byte spread; 32 contiguous k-bytes per (col,tap) = 2 ds_write_b128.
// LIF scan needs all 16 t of one (oc,px) in one thread -> f64 round-trip
// through LDS OT (C-layout cols are t).
// ---------------------------------------------------------------------------
__global__ __launch_bounds__(256, 2) void conv_mfma(
    const u16* __restrict__ in, const signed char* __restrict__ Adig,
    const float* __restrict__ b, const u16* __restrict__ res,
    u16* __restrict__ out) {
  __shared__ alignas(16) signed char S[128][336];  // 43008 B, stride 336=21*16
  __shared__ alignas(16) double OT[4][2][32][18];  // 36864 B

  int bidx = blockIdx.x;
  int xq = bidx & 3; int b2 = bidx >> 2;
  int y0 = b2 % 28;  int n = b2 / 28;
  int x0 = xq * 8;
  int valid_px = (x0 + 8 <= 28) ? 8 : (28 - x0);

  int tid = threadIdx.x;
  int lane = tid & 63;
  int wid = tid >> 6;   // wave 0..3
  int g = tid >> 5;     // 32-lane group 0..7
  int gl = tid & 31;    // lane-in-group = input channel c

  // ---- S build: 30 tasks = (3 input rows) x (10 abs-x positions) ----
  const u16* inn = in + (size_t)n * 32 * 28 * 28;
  for (int task = g; task < 30; task += 8) {
    int r = task / 10;   // ky
    int xa = task % 10;  // x - (x0-1)
    int y = y0 - 1 + r;
    int x = x0 - 1 + xa;
    u32 v = 0;
    if ((unsigned)y < 28u && (unsigned)x < 28u)
      v = (u32)inn[((size_t)gl * 28 + y) * 28 + x];
    // 32x32 bit transpose across the 32-lane group: after this, lane t
    // holds bit c = (bit t of mask[c]).  Bits t>=16 are zero.
    const u32 MK[5] = {0x0000FFFFu, 0x00FF00FFu, 0x0F0F0F0Fu,
                       0x33333333u, 0x55555555u};
#pragma unroll
    for (int i = 0; i < 5; ++i) {
      int s = 16 >> i;
      u32 mk = MK[i];
      u32 p = (u32)__shfl_xor((int)v, s);
      v = ((gl & s) == 0) ? ((v & mk) | ((p & mk) << s))
                          : ((v & ~mk) | ((p & ~mk) >> s));
    }
    if ((gl & 16) == 0) {
      int t = gl & 15;
      u32 dw[8];
#pragma unroll
      for (int d = 0; d < 8; ++d) {
        u32 nib = (v >> (4 * d)) & 0xFu;
        dw[d] = (nib * 0x00204081u) & 0x01010101u;  // 4 bits -> 4 bytes
      }
#pragma unroll
      for (int kx = 0; kx < 3; ++kx) {
        int px = xa - kx;
        if (px >= 0 && px < 8) {
          int col = px * 16 + t;
          int kb = (r * 3 + kx) * 32;
          i32x4 lo = {(int)dw[0], (int)dw[1], (int)dw[2], (int)dw[3]};
          i32x4 hi = {(int)dw[4], (int)dw[5], (int)dw[6], (int)dw[7]};
          *(i32x4*)&S[col][kb] = lo;
          *(i32x4*)&S[col][kb + 16] = hi;
        }
      }
    }
  }
  __syncthreads();

  // ---- MFMA phase: wave handles subtiles s0, s0+1 (= pixels) ----
  int s0 = wid * 2;
  int m16 = lane & 15;
  int kg = (lane >> 4) & 3;

  i32x4 Bf[2][5];
#pragma unroll
  for (int s2 = 0; s2 < 2; ++s2) {
    int col = (s0 + s2) * 16 + m16;
#pragma unroll
    for (int kc = 0; kc < 5; ++kc)
      Bf[s2][kc] = *(const i32x4*)&S[col][kc * 64 + kg * 16];
  }

  i32x4 acc[2][2][6];
#pragma unroll
  for (int s2 = 0; s2 < 2; ++s2)
#pragma unroll
    for (int Mt = 0; Mt < 2; ++Mt)
#pragma unroll
      for (int p = 0; p < 6; ++p) acc[s2][Mt][p] = (i32x4){0, 0, 0, 0};

#pragma unroll
  for (int p = 0; p < 6; ++p) {
#pragma unroll
    for (int kc = 0; kc < 5; ++kc) {
      int koff = kc * 64 + kg * 16;
      i32x4 A0 = *(const i32x4*)&Adig[((size_t)(p * 32 + m16)) * 320 + koff];
      i32x4 A1 =
          *(const i32x4*)&Adig[((size_t)(p * 32 + 16 + m16)) * 320 + koff];
#pragma unroll
      for (int s2 = 0; s2 < 2; ++s2) {
        acc[s2][0][p] = __builtin_amdgcn_mfma_i32_16x16x64_i8(
            A0, Bf[s2][kc], acc[s2][0][p], 0, 0, 0);
        acc[s2][1][p] = __builtin_amdgcn_mfma_i32_16x16x64_i8(
            A1, Bf[s2][kc], acc[s2][1][p], 0, 0, 0);
      }
    }
  }

  // ---- epilogue: exact f64 recombination, via LDS to regroup t ----
  const double SC[6] = {0x1p-45, 0x1p-37, 0x1p-29, 0x1p-21, 0x1p-13, 0x1p-5};
  int t = m16;
  int rb = kg * 4;
#pragma unroll
  for (int s2 = 0; s2 < 2; ++s2)
#pragma unroll
    for (int Mt = 0; Mt < 2; ++Mt)
#pragma unroll
      for (int r = 0; r < 4; ++r) {
        int oc = Mt * 16 + rb + r;
        double vs = (double)b[oc];
#pragma unroll
        for (int p = 0; p < 6; ++p)
          vs = fma((double)acc[s2][Mt][p][r], SC[p], vs);
        OT[wid][s2][oc][t] = vs;
      }
  __syncthreads();

  // ---- LIF scan: 64 lanes = 2 subtiles x 32 oc ----
  int sl = lane >> 5;
  int oc = lane & 31;
  int px = s0 + sl;
  if (px < valid_px) {
    size_t oidx = (((size_t)n * 32 + oc) * 28 + y0) * 28 + (x0 + px);
    u32 rm = res ? (u32)res[oidx] : 0u;
    double u = 0.0;
    u32 mo = 0;
#pragma unroll
    for (int tt = 0; tt < TT; ++tt) {
      double a = OT[wid][sl][oc][tt] + (((rm >> tt) & 1u) ? 1.0 : 0.0);
      u += a;
      if (u >= 1.0) { mo |= (1u << tt); u -= 1.0; }
    }
    out[oidx] = (u16)mo;
  }
}

// ---------------------------------------------------------------------------
// FMA-formulated f64 conv3x3 (kept for L6: 16ch, 14x14 — small).
// ---------------------------------------------------------------------------
template <int CIN, int COUT, int H, int W>
__global__ __launch_bounds__((COUT / 4) * 64) void conv3x3_fma(
    const u16* __restrict__ in, const float* __restrict__ w,
    const float* __restrict__ b, const u16* __restrict__ res,
    u16* __restrict__ out) {
  constexpr int TX = 16, TY = 4;
  constexpr int TILESX = (W + TX - 1) / TX;
  constexpr int TILESY = (H + TY - 1) / TY;
  constexpr int HALO = 6 * (TX + 2);
  constexpr int BLOCK = (COUT / 4) * 64;
  __shared__ u16 lds[CIN][6][TX + 2];

  int blk = blockIdx.x;
  int tx = blk % TILESX; int t1 = blk / TILESX;
  int ty = t1 % TILESY;  int n  = t1 / TILESY;
  int x0 = tx * TX, y0 = ty * TY;

  int tid = threadIdx.x;

  const u16* inn = in + (size_t)n * CIN * H * W;
  for (int idx = tid; idx < CIN * HALO; idx += BLOCK) {
    int c = idx / HALO; int rem = idx % HALO;
    int r = rem / (TX + 2); int cc = rem % (TX + 2);
    int gy = y0 - 1 + r, gx = x0 - 1 + cc;
    u16 v = 0;
    if ((unsigned)gy < (unsigned)H && (unsigned)gx < (unsigned)W)
      v = inn[(size_t)c * H * W + gy * W + gx];
    lds[c][r][cc] = v;
  }
  __syncthreads();

  int lane = tid & 63;
  int og = __builtin_amdgcn_readfirstlane(tid >> 6);
  int oc0 = og * 4;
  int px = lane & 15, py = lane >> 4;

  double acc[4][TT];
#pragma unroll
  for (int j = 0; j < 4; ++j) {
    double bv = (double)b[oc0 + j];
#pragma unroll
    for (int t = 0; t < TT; ++t) acc[j][t] = bv;
  }

  for (int c = 0; c < CIN; ++c) {
    const float* wc = w + ((size_t)oc0 * CIN + c) * 9;
#pragma unroll
    for (int ky = 0; ky < 3; ++ky) {
#pragma unroll
      for (int kx = 0; kx < 3; ++kx) {
        u32 m = lds[c][py + ky][px + kx];
        int ko = ky * 3 + kx;
        double wh0 = 0.5 * (double)wc[ko];
        double wh1 = 0.5 * (double)wc[CIN * 9 + ko];
        double wh2 = 0.5 * (double)wc[2 * CIN * 9 + ko];
        double wh3 = 0.5 * (double)wc[3 * CIN * 9 + ko];
#pragma unroll
        for (int t = 0; t < TT; ++t) {
          u32 hi = (m << (30 - t)) & 0x40000000u;
          double bf = __hiloint2double((int)hi, 0);
          acc[0][t] = fma(wh0, bf, acc[0][t]);
          acc[1][t] = fma(wh1, bf, acc[1][t]);
          acc[2][t] = fma(wh2, bf, acc[2][t]);
          acc[3][t] = fma(wh3, bf, acc[3][t]);
        }
      }
    }
  }

  int gx = x0 + px, gy = y0 + py;
  if (gx < W && gy < H) {
#pragma unroll
    for (int j = 0; j < 4; ++j) {
      size_t oidx = ((size_t)(n * COUT + oc0 + j) * H + gy) * W + gx;
      double u = 0.0;
      u32 mo = 0;
      if (res) {
        u32 rm = res[oidx];
#pragma unroll
        for (int t = 0; t < TT; ++t) {
          double a = acc[j][t] + (((rm >> t) & 1u) ? 1.0 : 0.0);
          u += a;
          if (u >= 1.0) { mo |= (1u << t); u -= 1.0; }
        }
      } else {
#pragma unroll
        for (int t = 0; t < TT; ++t) {
          u += acc[j][t];
          if (u >= 1.0) { mo |= (1u << t); u -= 1.0; }
        }
      }
      out[oidx] = (u16)mo;
    }
  }
}

// ---------------------------------------------------------------------------
// 2x2 average pool on packed binary input + spike.
// ---------------------------------------------------------------------------
__global__ __launch_bounds__(256) void pool_spike(
    const u16* __restrict__ in, u16* __restrict__ out) {
  int idx = blockIdx.x * 256 + threadIdx.x;
  const int total = 128 * 32 * 14 * 14;
  if (idx >= total) return;
  int xx = idx % 14; int t1 = idx / 14;
  int yy = t1 % 14;  int t2 = t1 / 14;
  int c  = t2 % 32;  int n  = t2 / 32;

  const u16* base = in + ((size_t)(n * 32 + c) * 28 + yy * 2) * 28 + xx * 2;
  u32 m00 = base[0], m01 = base[1], m10 = base[28], m11 = base[29];

  double acc[TT];
#pragma unroll
  for (int t = 0; t < TT; ++t) {
    u32 s = ((m00 >> t) & 1u) + ((m01 >> t) & 1u) + ((m10 >> t) & 1u) +
            ((m11 >> t) & 1u);
    acc[t] = 0.25 * (double)s;
  }
  out[idx] = (u16)scan_spike(acc);
}

// ---------------------------------------------------------------------------
// Generic conv1x1 on packed binary input + optional residual + spike.
// ---------------------------------------------------------------------------
template <int CIN>
__global__ __launch_bounds__(256) void conv1x1_spike(
    const u16* __restrict__ in, const float* __restrict__ w,
    const float* __restrict__ b, const u16* __restrict__ res,
    u16* __restrict__ out, int N, int Cout, int HW) {
  int idx = blockIdx.x * 256 + threadIdx.x;
  int total = N * Cout * HW;
  if (idx >= total) return;
  int p = idx % HW; int t1 = idx / HW;
  int o = t1 % Cout; int n = t1 / Cout;

  double acc[TT];
  double bv = (double)b[o];
#pragma unroll
  for (int t = 0; t < TT; ++t) acc[t] = bv;

  const u16* inp = in + (size_t)n * CIN * HW + p;
  const float* wo = w + (size_t)o * CIN;
#pragma unroll 4
  for (int c = 0; c < CIN; ++c) {
    u32 m = inp[c * HW];
    double wh = 0.5 * (double)wo[c];
#pragma unroll
    for (int t = 0; t < TT; ++t) {
      u32 hi = (m << (30 - t)) & 0x40000000u;
      acc[t] = fma(wh, __hiloint2double((int)hi, 0), acc[t]);
    }
  }
  if (res) {
    u32 m = res[idx];
#pragma unroll
    for (int t = 0; t < TT; ++t) acc[t] += ((m >> t) & 1u) ? 1.0 : 0.0;
  }
  out[idx] = (u16)scan_spike(acc);
}

// ---------------------------------------------------------------------------
// Dense 6272 -> 128 + spike. One wave per (n,o).
// ---------------------------------------------------------------------------
__global__ __launch_bounds__(64) void dense1_spike(
    const u16* __restrict__ in, const float* __restrict__ w,
    const float* __restrict__ b, u16* __restrict__ out) {
  int bid = blockIdx.x;
  int o = bid & 127;
  int n = bid >> 7;
  int lane = threadIdx.x;

  double acc[TT];
#pragma unroll
  for (int t = 0; t < TT; ++t) acc[t] = 0.0;

  const u16* inn = in + (size_t)n * 6272;
  const float* wo = w + (size_t)o * 6272;
  for (int f = lane; f < 6272; f += 64) {
    u32 m = inn[f];
    double wh = 0.5 * (double)wo[f];
#pragma unroll
    for (int t = 0; t < TT; ++t) {
      u32 hi = (m << (30 - t)) & 0x40000000u;
      acc[t] = fma(wh, __hiloint2double((int)hi, 0), acc[t]);
    }
  }
#pragma unroll
  for (int t = 0; t < TT; ++t) {
#pragma unroll
    for (int off = 32; off > 0; off >>= 1) acc[t] += __shfl_down(acc[t], off);
  }
  if (lane == 0) {
    double bv = (double)b[o];
    double u = 0.0;
    u32 mo = 0;
#pragma unroll
    for (int t = 0; t < TT; ++t) {
      u += acc[t] + bv;
      if (u >= 1.0) { mo |= (1u << t); u -= 1.0; }
    }
    out[n * 128 + o] = (u16)mo;
  }
}

// ---------------------------------------------------------------------------
// Dense 128 -> 10 + spike + firing-rate output. out: [128,10] f32
// ---------------------------------------------------------------------------
__global__ __launch_bounds__(64) void dense2_out(
    const u16* __restrict__ in, const float* __restrict__ w,
    const float* __restrict__ b, float* __restrict__ out) {
  int idx = blockIdx.x * 64 + threadIdx.x;
  if (idx >= 1280) return;
  int o = idx % 10;
  int n = idx / 10;

  double acc[TT];
  double bv = (double)b[o];
#pragma unroll
  for (int t = 0; t < TT; ++t) acc[t] = bv;

  const u16* inn = in + (size_t)n * 128;
  const float* wo = w + (size_t)o * 128;
  for (int f = 0; f < 128; ++f) {
    u32 m = inn[f];
    double wv = (double)wo[f];
#pragma unroll
    for (int t = 0; t < TT; ++t) acc[t] += ((m >> t) & 1u) ? wv : 0.0;
  }
  u32 mo = scan_spike(acc);
  out[idx] = (float)__popc(mo) * 0.0625f;
}

// ---------------------------------------------------------------------------
extern "C" void kernel_launch(void* const* d_in, const int* in_sizes, int n_in,
                              void* d_out, int out_size, void* d_ws,
                              size_t ws_size, hipStream_t stream) {
  const float* x   = (const float*)d_in[0];
  const float* w1  = (const float*)d_in[1];
  const float* b1  = (const float*)d_in[2];
  const float* w2  = (const float*)d_in[3];
  const float* b2  = (const float*)d_in[4];
  const float* w3  = (const float*)d_in[5];
  const float* b3  = (const float*)d_in[6];
  const float* w4  = (const float*)d_in[7];
  const float* b4  = (const float*)d_in[8];
  const float* w5  = (const float*)d_in[9];
  const float* b5  = (const float*)d_in[10];
  const float* w6  = (const float*)d_in[11];
  const float* b6  = (const float*)d_in[12];
  const float* wf1 = (const float*)d_in[13];
  const float* bf1 = (const float*)d_in[14];
  const float* wf2 = (const float*)d_in[15];
  const float* bf2 = (const float*)d_in[16];
  float* out = (float*)d_out;

  // Workspace layout (packed u16 spike masks + i8 digit planes)
  u16* s1 = (u16*)d_ws;            // [128,32,28,28]
  u16* s2 = s1 + 3211264;
  u16* s3 = s2 + 3211264;
  u16* s4 = s3 + 3211264;          // [128,32,14,14]
  u16* s5 = s4 + 802816;           // [128,16,14,14]
  u16* s6 = s5 + 401408;
  u16* s7 = s6 + 401408;           // [128,32,14,14]
  u16* s8 = s7 + 802816;           // [128,128]
  // digit planes, 256B-aligned after s8 (u16 total = 24,517,120 B)
  signed char* Adig2 = (signed char*)d_ws + 24517376;  // 61440 B
  signed char* Adig3 = Adig2 + 61440;                  // 61440 B

  // Digit prep for the two MFMA convs (tiny)
  prep_digits<<<32, 32, 0, stream>>>(w2, Adig2);
  prep_digits<<<32, 32, 0, stream>>>(w3, Adig3);

  // L1: conv3x3 1->32 pad1 + spike (f64 vector)
  conv1_spike<<<(3211264 + 255) / 256, 256, 0, stream>>>(x, w1, b1, s1);
  // L2: conv3x3 32->32 pad1 + spike (exact i8 MFMA)
  conv_mfma<<<128 * 28 * 4, 256, 0, stream>>>(s1, Adig2, b2, nullptr, s2);
  // L3: conv3x3 32->32 pad1 + residual(s1) + spike (exact i8 MFMA)
  conv_mfma<<<128 * 28 * 4, 256, 0, stream>>>(s2, Adig3, b3, s1, s3);
  // L4: avgpool2 + spike
  pool_spike<<<(802816 + 255) / 256, 256, 0, stream>>>(s3, s4);
  // L5: conv1x1 32->16 + spike
  conv1x1_spike<32><<<(401408 + 255) / 256, 256, 0, stream>>>(
      s4, w4, b4, nullptr, s5, 128, 16, 196);
  // L6: conv3x3 16->16 pad1 + spike (f64 FMA, small)
  conv3x3_fma<16, 16, 14, 14><<<128 * 4 * 1, 256, 0, stream>>>(
      s5, w5, b5, nullptr, s6);
  // L7: conv1x1 16->32 + residual(s4) + spike
  conv1x1_spike<16><<<(802816 + 255) / 256, 256, 0, stream>>>(
      s6, w6, b6, s4, s7, 128, 32, 196);
  // L8: dense 6272->128 + spike
  dense1_spike<<<16384, 64, 0, stream>>>(s7, wf1, bf1, s8);
  // L9: dense 128->10 + spike + rate
  dense2_out<<<(1280 + 63) / 64, 64, 0, stream>>>(s8, wf2, bf2, out);
}

// Round 4
// 828.391 us; speedup vs baseline: 4.9772x; 1.3868x over previous
//
#include <hip/hip_runtime.h>

typedef unsigned short u16;
typedef unsigned int u32;
typedef __attribute__((ext_vector_type(4))) int i32x4;
typedef __attribute__((ext_vector_type(16))) int i32x16;

#define TT 16

// ---------------------------------------------------------------------------
// f64 LIF scan (kept for the f64 kernels). R2/R3: absmax=0.0 establishes
// order-freedom; margins >> f64 noise.
// ---------------------------------------------------------------------------
__device__ __forceinline__ u32 scan_spike(const double* acc) {
  double u = 0.0;
  u32 m = 0;
#pragma unroll
  for (int t = 0; t < TT; ++t) {
    u += acc[t];
    if (u >= 1.0) { m |= (1u << t); u -= 1.0; }
  }
  return m;
}

__device__ __forceinline__ long long shfl_xor64(long long v, int m) {
  int lo = __shfl_xor((int)(v & 0xffffffffLL), m);
  int hi = __shfl_xor((int)(v >> 32), m);
  return ((long long)hi << 32) | (u32)lo;
}

// ---------------------------------------------------------------------------
// Layer 1: conv3x3 pad1, Cin=1 (continuous f32 input) + spike. (R3-verbatim)
// ---------------------------------------------------------------------------
__global__ __launch_bounds__(256) void conv1_spike(
    const float* __restrict__ x, const float* __restrict__ w,
    const float* __restrict__ b, u16* __restrict__ out) {
  int idx = blockIdx.x * 256 + threadIdx.x;
  const int total = 128 * 32 * 28 * 28;
  if (idx >= total) return;
  int xx = idx % 28; int t1 = idx / 28;
  int yy = t1 % 28;  int t2 = t1 / 28;
  int o  = t2 % 32;  int n  = t2 / 32;

  double acc[TT];
  double bv = (double)b[o];
#pragma unroll
  for (int t = 0; t < TT; ++t) acc[t] = bv;

#pragma unroll
  for (int dy = 0; dy < 3; ++dy) {
    int yi = yy + dy - 1;
    if ((unsigned)yi >= 28u) continue;
#pragma unroll
    for (int dx = 0; dx < 3; ++dx) {
      int xi = xx + dx - 1;
      if ((unsigned)xi >= 28u) continue;
      double wv = (double)w[o * 9 + dy * 3 + dx];
      const float* xp = x + ((size_t)(n * 28 + yi) * 28 + xi) * TT;
#pragma unroll
      for (int t = 0; t < TT; ++t) acc[t] += wv * (double)xp[t];
    }
  }
  out[idx] = (u16)scan_spike(acc);
}

// ---------------------------------------------------------------------------
// Digit prep in MFMA B-frag order. X = rint(w*2^45) decomposed into 6 signed
// base-256 digits (exact path, R3-verified absmax=0). B-frag for
// mfma_i32_32x32x32_i8: col(oc)=lane&31, k-bytes c = (lane>>5)*16+j.
// Wd[((p*9+tap)*64 + lane)*16 + j] = digit_p(w[oc][c][tap]).
// ---------------------------------------------------------------------------
__global__ void prep_digits_frag(const float* __restrict__ w,
                                 signed char* __restrict__ Wd) {
  int tap = blockIdx.x;    // 9
  int lane = threadIdx.x;  // 64
  int oc = lane & 31, kh = lane >> 5;
  for (int j = 0; j < 16; ++j) {
    int c = kh * 16 + j;
    double xv = ldexp((double)w[((size_t)(oc * 32 + c)) * 9 + tap], 45);
    long long X = (long long)rint(xv);
    for (int p = 0; p < 6; ++p) {
      int d = (int)((X + 128) & 255) - 128;
      Wd[((size_t)((p * 9 + tap) * 64 + lane)) * 16 + j] = (signed char)d;
      X = (X - (long long)d) >> 8;
    }
  }
}

// ---------------------------------------------------------------------------
// Expand packed u16 masks -> byte tensor T[nloc][30][30][16][32] (zero-padded
// border left untouched; memset once per launch). 8 sites per 256-thr block;
// 32-lane group per site: lanes=c load masks, 5-stage 32x32 bit transpose
// (R3-proven), lanes t<16 write 32 contiguous c-bytes (2x dwordx4).
// ---------------------------------------------------------------------------
__global__ __launch_bounds__(256) void expand_masks(
    const u16* __restrict__ s, signed char* __restrict__ T, int nbase) {
  int site = blockIdx.x * 8 + (threadIdx.x >> 5);
  int gl = threadIdx.x & 31;
  int x = site % 28; int t1 = site / 28;
  int y = t1 % 28;   int nloc = t1 / 28;

  u32 v = (u32)s[(((size_t)(nbase + nloc) * 32 + gl) * 28 + y) * 28 + x];
  const u32 MK[5] = {0x0000FFFFu, 0x00FF00FFu, 0x0F0F0F0Fu,
                     0x33333333u, 0x55555555u};
#pragma unroll
  for (int i = 0; i < 5; ++i) {
    int sh = 16 >> i;
    u32 mk = MK[i];
    u32 p = (u32)__shfl_xor((int)v, sh);
    v = ((gl & sh) == 0) ? ((v & mk) | ((p & mk) << sh))
                         : ((v & ~mk) | ((p & ~mk) >> sh));
  }
  if (gl < 16) {
    u32 dw[8];
#pragma unroll
    for (int d = 0; d < 8; ++d) {
      u32 nib = (v >> (4 * d)) & 0xFu;
      dw[d] = (nib * 0x00204081u) & 0x01010101u;
    }
    signed char* Tp =
        T + (((size_t)nloc * 30 + y + 1) * 30 + (x + 1)) * 512 + gl * 32;
    *(i32x4*)Tp = (i32x4){(int)dw[0], (int)dw[1], (int)dw[2], (int)dw[3]};
    *(i32x4*)(Tp + 16) = (i32x4){(int)dw[4], (int)dw[5], (int)dw[6], (int)dw[7]};
  }
}

// ---------------------------------------------------------------------------
// Integer epilogue: plane-recombined exact i64 conv values live in cc[16]
// (C-layout rows). Exchange with lane^32 (same oc) so each lane owns all 16 t
// of one (oc,px); integer LIF scan with TH = 2^45. Exact: weights are
// rint(w*2^45) (err<=2^-46 per weight vs ~1e-8 min margins), biases zero.
// C row = (reg&3) + 8*(reg>>2) + 4*(lane>>5): px=row>>4 -> regs 0-7 px0,
// 8-15 px1; t = row&15. h=0 keeps px0 (sends regs 8-15), h=1 keeps px1
// (sends regs 0-7); u[t]: sel=(t>>2)&1: (sel^h)? recv : own[8h+lo].
// ---------------------------------------------------------------------------
template <bool WRITE_T, bool HAS_RES>
__device__ __forceinline__ void epi_i8(long long (&cc)[16], int h, int oc,
                                       int px_out, int y, int nloc, int n_g,
                                       const float* bias,
                                       const u16* __restrict__ res,
                                       signed char* __restrict__ Tout,
                                       u16* __restrict__ mout) {
  long long recv[8];
#pragma unroll
  for (int j = 0; j < 8; ++j) {
    long long send = h ? cc[j] : cc[8 + j];
    recv[j] = shfl_xor64(send, 32);
  }
  long long B45 = (long long)rint((double)bias[oc] * 35184372088832.0);
  u32 rm = 0;
  if (HAS_RES && px_out < 28)
    rm = res[(((size_t)n_g * 32 + oc) * 28 + y) * 28 + px_out];
  long long u = 0;
  u32 mo = 0;
  const long long TH = 1LL << 45;
#pragma unroll
  for (int t = 0; t < TT; ++t) {
    int lo = (t & 3) + 4 * (t >> 3);
    int sel = (t >> 2) & 1;
    long long own = h ? cc[8 + lo] : cc[lo];
    long long ut = (sel ^ h) ? recv[lo] : own;
    ut += B45 + (((rm >> t) & 1u) ? TH : 0);
    u += ut;
    if (u >= TH) { mo |= (1u << t); u -= TH; }
  }
  if (px_out < 28) {
    if (WRITE_T) {
      signed char* Tp =
          Tout + (((size_t)nloc * 30 + y + 1) * 30 + px_out + 1) * 512 + oc;
#pragma unroll
      for (int t = 0; t < TT; ++t)
        Tp[t * 32] = (signed char)((mo >> t) & 1u);
    } else {
      mout[(((size_t)n_g * 32 + oc) * 28 + y) * 28 + px_out] = (u16)mo;
    }
  }
}

// ---------------------------------------------------------------------------
// conv3x3 32->32 pad1 via exact i8 32x32x32 MFMA. A = spike bytes from padded
// T (M = 2px x 16t), B = weight digits from LDS (N = 32 oc, K = 32 c); 9 taps
// accumulate, 6 planes recombined in i64. Wave owns 2 px-tiles (4 px) so each
// B ds_read feeds 2 MFMAs. Block 256 = 4 waves = 16 px of one (nloc, y) row.
// ---------------------------------------------------------------------------
template <bool WRITE_T, bool HAS_RES>
__global__ __launch_bounds__(256, 2) void conv_i8(
    const signed char* __restrict__ Tin, const signed char* __restrict__ Wd,
    const float* __restrict__ bias, const u16* __restrict__ res,
    signed char* __restrict__ Tout, u16* __restrict__ mout, int nbase) {
  __shared__ signed char WL[6 * 9 * 1024];  // 55296 B, frag-ordered
  int tid = threadIdx.x;
  for (int j = tid; j < 3456; j += 256)
    ((i32x4*)WL)[j] = ((const i32x4*)Wd)[j];
  __syncthreads();

  int blk = blockIdx.x;
  int xblk = blk & 1; int b2 = blk >> 1;
  int y = b2 % 28;    int nloc = b2 / 28;
  int lane = tid & 63, wid = tid >> 6;
  int h = lane >> 5, rowlane = lane & 31;
  int pxr = rowlane >> 4, tA = rowlane & 15;
  int pxb = xblk * 16 + wid * 4;

  // A-frags: row=(pxr,tA) via lane&31, k-half c via lane>>5. Padded coords.
  i32x4 A0[9], A1[9];
  const signed char* Tn = Tin + (size_t)nloc * (30 * 30 * 512);
#pragma unroll
  for (int ky = 0; ky < 3; ++ky)
#pragma unroll
    for (int kx = 0; kx < 3; ++kx) {
      int tap = ky * 3 + kx;
      int ypad = y + ky;
      int x0 = pxb + pxr + kx;     if (x0 > 29) x0 = 29;
      int x1 = pxb + 2 + pxr + kx; if (x1 > 29) x1 = 29;
      A0[tap] = *(const i32x4*)(Tn + ((size_t)(ypad * 30 + x0)) * 512 +
                                tA * 32 + h * 16);
      A1[tap] = *(const i32x4*)(Tn + ((size_t)(ypad * 30 + x1)) * 512 +
                                tA * 32 + h * 16);
    }

  long long c0[16], c1[16];
#pragma unroll
  for (int r = 0; r < 16; ++r) { c0[r] = 0; c1[r] = 0; }

#pragma unroll
  for (int p = 0; p < 6; ++p) {
    i32x16 a0 = {0, 0, 0, 0, 0, 0, 0, 0, 0, 0, 0, 0, 0, 0, 0, 0};
    i32x16 a1 = {0, 0, 0, 0, 0, 0, 0, 0, 0, 0, 0, 0, 0, 0, 0, 0};
#pragma unroll
    for (int tap = 0; tap < 9; ++tap) {
      i32x4 Bf = *(const i32x4*)&WL[((size_t)((p * 9 + tap) * 64 + lane)) * 16];
      a0 = __builtin_amdgcn_mfma_i32_32x32x32_i8(A0[tap], Bf, a0, 0, 0, 0);
      a1 = __builtin_amdgcn_mfma_i32_32x32x32_i8(A1[tap], Bf, a1, 0, 0, 0);
    }
#pragma unroll
    for (int r = 0; r < 16; ++r) {
      c0[r] += ((long long)a0[r]) << (8 * p);
      c1[r] += ((long long)a1[r]) << (8 * p);
    }
  }

  int n_g = nbase + nloc;
  int oc = rowlane;  // post-exchange ownership: (oc, px = base + h)
  epi_i8<WRITE_T, HAS_RES>(c0, h, oc, pxb + h, y, nloc, n_g, bias, res, Tout,
                           mout);
  epi_i8<WRITE_T, HAS_RES>(c1, h, oc, pxb + 2 + h, y, nloc, n_g, bias, res,
                           Tout, mout);
}

// ---------------------------------------------------------------------------
// 2x2 average pool + spike (R3-verbatim).
// ---------------------------------------------------------------------------
__global__ __launch_bounds__(256) void pool_spike(
    const u16* __restrict__ in, u16* __restrict__ out) {
  int idx = blockIdx.x * 256 + threadIdx.x;
  const int total = 128 * 32 * 14 * 14;
  if (idx >= total) return;
  int xx = idx % 14; int t1 = idx / 14;
  int yy = t1 % 14;  int t2 = t1 / 14;
  int c  = t2 % 32;  int n  = t2 / 32;

  const u16* base = in + ((size_t)(n * 32 + c) * 28 + yy * 2) * 28 + xx * 2;
  u32 m00 = base[0], m01 = base[1], m10 = base[28], m11 = base[29];

  double acc[TT];
#pragma unroll
  for (int t = 0; t < TT; ++t) {
    u32 s = ((m00 >> t) & 1u) + ((m01 >> t) & 1u) + ((m10 >> t) & 1u) +
            ((m11 >> t) & 1u);
    acc[t] = 0.25 * (double)s;
  }
  out[idx] = (u16)scan_spike(acc);
}

// ---------------------------------------------------------------------------
// conv1x1 on packed binary input + optional residual + spike (R3-verbatim).
// ---------------------------------------------------------------------------
template <int CIN>
__global__ __launch_bounds__(256) void conv1x1_spike(
    const u16* __restrict__ in, const float* __restrict__ w,
    const float* __restrict__ b, const u16* __restrict__ res,
    u16* __restrict__ out, int N, int Cout, int HW) {
  int idx = blockIdx.x * 256 + threadIdx.x;
  int total = N * Cout * HW;
  if (idx >= total) return;
  int p = idx % HW; int t1 = idx / HW;
  int o = t1 % Cout; int n = t1 / Cout;

  double acc[TT];
  double bv = (double)b[o];
#pragma unroll
  for (int t = 0; t < TT; ++t) acc[t] = bv;

  const u16* inp = in + (size_t)n * CIN * HW + p;
  const float* wo = w + (size_t)o * CIN;
#pragma unroll 4
  for (int c = 0; c < CIN; ++c) {
    u32 m = inp[c * HW];
    double wh = 0.5 * (double)wo[c];
#pragma unroll
    for (int t = 0; t < TT; ++t) {
      u32 hi = (m << (30 - t)) & 0x40000000u;
      acc[t] = fma(wh, __hiloint2double((int)hi, 0), acc[t]);
    }
  }
  if (res) {
    u32 m = res[idx];
#pragma unroll
    for (int t = 0; t < TT; ++t) acc[t] += ((m >> t) & 1u) ? 1.0 : 0.0;
  }
  out[idx] = (u16)scan_spike(acc);
}

// ---------------------------------------------------------------------------
// f64 FMA conv3x3 (L6: 16ch 14x14, small) (R3-verbatim).
// ---------------------------------------------------------------------------
template <int CIN, int COUT, int H, int W>
__global__ __launch_bounds__((COUT / 4) * 64) void conv3x3_fma(
    const u16* __restrict__ in, const float* __restrict__ w,
    const float* __restrict__ b, const u16* __restrict__ res,
    u16* __restrict__ out) {
  constexpr int TX = 16, TY = 4;
  constexpr int TILESX = (W + TX - 1) / TX;
  constexpr int TILESY = (H + TY - 1) / TY;
  constexpr int HALO = 6 * (TX + 2);
  constexpr int BLOCK = (COUT / 4) * 64;
  __shared__ u16 lds[CIN][6][TX + 2];

  int blk = blockIdx.x;
  int tx = blk % TILESX; int t1 = blk / TILESX;
  int ty = t1 % TILESY;  int n  = t1 / TILESY;
  int x0 = tx * TX, y0 = ty * TY;

  int tid = threadIdx.x;

  const u16* inn = in + (size_t)n * CIN * H * W;
  for (int idx = tid; idx < CIN * HALO; idx += BLOCK) {
    int c = idx / HALO; int rem = idx % HALO;
    int r = rem / (TX + 2); int cc = rem % (TX + 2);
    int gy = y0 - 1 + r, gx = x0 - 1 + cc;
    u16 v = 0;
    if ((unsigned)gy < (unsigned)H && (unsigned)gx < (unsigned)W)
      v = inn[(size_t)c * H * W + gy * W + gx];
    lds[c][r][cc] = v;
  }
  __syncthreads();

  int lane = tid & 63;
  int og = __builtin_amdgcn_readfirstlane(tid >> 6);
  int oc0 = og * 4;
  int px = lane & 15, py = lane >> 4;

  double acc[4][TT];
#pragma unroll
  for (int j = 0; j < 4; ++j) {
    double bv = (double)b[oc0 + j];
#pragma unroll
    for (int t = 0; t < TT; ++t) acc[j][t] = bv;
  }

  for (int c = 0; c < CIN; ++c) {
    const float* wc = w + ((size_t)oc0 * CIN + c) * 9;
#pragma unroll
    for (int ky = 0; ky < 3; ++ky) {
#pragma unroll
      for (int kx = 0; kx < 3; ++kx) {
        u32 m = lds[c][py + ky][px + kx];
        int ko = ky * 3 + kx;
        double wh0 = 0.5 * (double)wc[ko];
        double wh1 = 0.5 * (double)wc[CIN * 9 + ko];
        double wh2 = 0.5 * (double)wc[2 * CIN * 9 + ko];
        double wh3 = 0.5 * (double)wc[3 * CIN * 9 + ko];
#pragma unroll
        for (int t = 0; t < TT; ++t) {
          u32 hi = (m << (30 - t)) & 0x40000000u;
          double bf = __hiloint2double((int)hi, 0);
          acc[0][t] = fma(wh0, bf, acc[0][t]);
          acc[1][t] = fma(wh1, bf, acc[1][t]);
          acc[2][t] = fma(wh2, bf, acc[2][t]);
          acc[3][t] = fma(wh3, bf, acc[3][t]);
        }
      }
    }
  }

  int gx = x0 + px, gy = y0 + py;
  if (gx < W && gy < H) {
#pragma unroll
    for (int j = 0; j < 4; ++j) {
      size_t oidx = ((size_t)(n * COUT + oc0 + j) * H + gy) * W + gx;
      double u = 0.0;
      u32 mo = 0;
      if (res) {
        u32 rm = res[oidx];
#pragma unroll
        for (int t = 0; t < TT; ++t) {
          double a = acc[j][t] + (((rm >> t) & 1u) ? 1.0 : 0.0);
          u += a;
          if (u >= 1.0) { mo |= (1u << t); u -= 1.0; }
        }
      } else {
#pragma unroll
        for (int t = 0; t < TT; ++t) {
          u += acc[j][t];
          if (u >= 1.0) { mo |= (1u << t); u -= 1.0; }
        }
      }
      out[oidx] = (u16)mo;
    }
  }
}

// ---------------------------------------------------------------------------
// Dense 6272 -> 128 + spike (R3-verbatim).
// ---------------------------------------------------------------------------
__global__ __launch_bounds__(64) void dense1_spike(
    const u16* __restrict__ in, const float* __restrict__ w,
    const float* __restrict__ b, u16* __restrict__ out) {
  int bid = blockIdx.x;
  int o = bid & 127;
  int n = bid >> 7;
  int lane = threadIdx.x;

  double acc[TT];
#pragma unroll
  for (int t = 0; t < TT; ++t) acc[t] = 0.0;

  const u16* inn = in + (size_t)n * 6272;
  const float* wo = w + (size_t)o * 6272;
  for (int f = lane; f < 6272; f += 64) {
    u32 m = inn[f];
    double wh = 0.5 * (double)wo[f];
#pragma unroll
    for (int t = 0; t < TT; ++t) {
      u32 hi = (m << (30 - t)) & 0x40000000u;
      acc[t] = fma(wh, __hiloint2double((int)hi, 0), acc[t]);
    }
  }
#pragma unroll
  for (int t = 0; t < TT; ++t) {
#pragma unroll
    for (int off = 32; off > 0; off >>= 1) acc[t] += __shfl_down(acc[t], off);
  }
  if (lane == 0) {
    double bv = (double)b[o];
    double u = 0.0;
    u32 mo = 0;
#pragma unroll
    for (int t = 0; t < TT; ++t) {
      u += acc[t] + bv;
      if (u >= 1.0) { mo |= (1u << t); u -= 1.0; }
    }
    out[n * 128 + o] = (u16)mo;
  }
}

// ---------------------------------------------------------------------------
// Dense 128 -> 10 + spike + rate (R3-verbatim).
// ---------------------------------------------------------------------------
__global__ __launch_bounds__(64) void dense2_out(
    const u16* __restrict__ in, const float* __restrict__ w,
    const float* __restrict__ b, float* __restrict__ out) {
  int idx = blockIdx.x * 64 + threadIdx.x;
  if (idx >= 1280) return;
  int o = idx % 10;
  int n = idx / 10;

  double acc[TT];
  double bv = (double)b[o];
#pragma unroll
  for (int t = 0; t < TT; ++t) acc[t] = bv;

  const u16* inn = in + (size_t)n * 128;
  const float* wo = w + (size_t)o * 128;
  for (int f = 0; f < 128; ++f) {
    u32 m = inn[f];
    double wv = (double)wo[f];
#pragma unroll
    for (int t = 0; t < TT; ++t) acc[t] += ((m >> t) & 1u) ? wv : 0.0;
  }
  u32 mo = scan_spike(acc);
  out[idx] = (float)__popc(mo) * 0.0625f;
}

// ---------------------------------------------------------------------------
extern "C" void kernel_launch(void* const* d_in, const int* in_sizes, int n_in,
                              void* d_out, int out_size, void* d_ws,
                              size_t ws_size, hipStream_t stream) {
  const float* x   = (const float*)d_in[0];
  const float* w1  = (const float*)d_in[1];
  const float* b1  = (const float*)d_in[2];
  const float* w2  = (const float*)d_in[3];
  const float* b2  = (const float*)d_in[4];
  const float* w3  = (const float*)d_in[5];
  const float* b3  = (const float*)d_in[6];
  const float* w4  = (const float*)d_in[7];
  const float* b4  = (const float*)d_in[8];
  const float* w5  = (const float*)d_in[9];
  const float* b5  = (const float*)d_in[10];
  const float* w6  = (const float*)d_in[11];
  const float* b6  = (const float*)d_in[12];
  const float* wf1 = (const float*)d_in[13];
  const float* bf1 = (const float*)d_in[14];
  const float* wf2 = (const float*)d_in[15];
  const float* bf2 = (const float*)d_in[16];
  float* out = (float*)d_out;

  // Workspace layout (byte offsets). ~47.3 MB total.
  char* W = (char*)d_ws;
  u16* s1 = (u16*)(W + 0);               // [128,32,28,28]  6,422,528 B
  u16* s3 = (u16*)(W + 6422528);         // [128,32,28,28]
  u16* s4 = (u16*)(W + 12845056);        // [128,32,14,14]  1,605,632 B
  u16* s5 = (u16*)(W + 14450688);        // [128,16,14,14]    802,816 B
  u16* s6 = (u16*)(W + 15253504);        // [128,16,14,14]
  u16* s7 = (u16*)(W + 16056320);        // [128,32,14,14]
  u16* s8 = (u16*)(W + 17661952);        // [128,128]          32,768 B
  signed char* Wd2 = (signed char*)(W + 17694720);  // 55,296 B frag digits
  signed char* Wd3 = (signed char*)(W + 17750016);
  signed char* T1c = (signed char*)(W + 17805312);  // 32x30x30x512 = 14,745,600
  signed char* T2c = (signed char*)(W + 32550912);  // same, ends 47,296,512

  const size_t TSZ = (size_t)32 * 30 * 30 * 512;

  // Weight digit prep (tiny) + zero T borders (interior rewritten per chunk)
  prep_digits_frag<<<9, 64, 0, stream>>>(w2, Wd2);
  prep_digits_frag<<<9, 64, 0, stream>>>(w3, Wd3);
  hipMemsetAsync(T1c, 0, TSZ, stream);
  hipMemsetAsync(T2c, 0, TSZ, stream);

  // L1: conv3x3 1->32 + spike (f64, full batch)
  conv1_spike<<<12544, 256, 0, stream>>>(x, w1, b1, s1);

  // L2/L3 in 4 n-chunks of 32 (bounds T buffers at 14.7 MB each)
  for (int k = 0; k < 4; ++k) {
    expand_masks<<<3136, 256, 0, stream>>>(s1, T1c, k * 32);
    conv_i8<true, false><<<1792, 256, 0, stream>>>(T1c, Wd2, b2, nullptr, T2c,
                                                   nullptr, k * 32);
    conv_i8<false, true><<<1792, 256, 0, stream>>>(T2c, Wd3, b3, s1, nullptr,
                                                   s3, k * 32);
  }

  // L4: avgpool2 + spike
  pool_spike<<<3136, 256, 0, stream>>>(s3, s4);
  // L5: conv1x1 32->16 + spike
  conv1x1_spike<32><<<1568, 256, 0, stream>>>(s4, w4, b4, nullptr, s5, 128, 16,
                                              196);
  // L6: conv3x3 16->16 + spike (f64)
  conv3x3_fma<16, 16, 14, 14><<<512, 256, 0, stream>>>(s5, w5, b5, nullptr, s6);
  // L7: conv1x1 16->32 + residual(s4) + spike
  conv1x1_spike<16><<<3136, 256, 0, stream>>>(s6, w6, b6, s4, s7, 128, 32, 196);
  // L8: dense 6272->128 + spike
  dense1_spike<<<16384, 64, 0, stream>>>(s7, wf1, bf1, s8);
  // L9: dense 128->10 + spike + rate
  dense2_out<<<20, 64, 0, stream>>>(s8, wf2, bf2, out);
}

// Round 5
// 677.690 us; speedup vs baseline: 6.0840x; 1.2224x over previous
//
#include <hip/hip_runtime.h>

typedef unsigned short u16;
typedef unsigned int u32;
typedef __attribute__((ext_vector_type(4))) int i32x4;
typedef __attribute__((ext_vector_type(16))) int i32x16;

#define TT 16

// ---------------------------------------------------------------------------
// f64 LIF scan (soft reset, THETA=1). R2/R3/R4: absmax=0.0 => order-free,
// margins >> f64 noise.
// ---------------------------------------------------------------------------
__device__ __forceinline__ u32 scan_spike(const double* acc) {
  double u = 0.0;
  u32 m = 0;
#pragma unroll
  for (int t = 0; t < TT; ++t) {
    u += acc[t];
    if (u >= 1.0) { m |= (1u << t); u -= 1.0; }
  }
  return m;
}

__device__ __forceinline__ long long shfl_xor64(long long v, int m) {
  int lo = __shfl_xor((int)(v & 0xffffffffLL), m);
  int hi = __shfl_xor((int)(v >> 32), m);
  return ((long long)hi << 32) | (u32)lo;
}

// ---------------------------------------------------------------------------
// Layer 1: conv3x3 pad1 Cin=1, LDS-staged, 4 oc per thread. Block = (n, y):
// stage rows y-1..y+1 (30 cols, border 0) of x[n][.][.][16t] into LDS
// (inner dim padded to 18 -> <=2-way banks = free). Thread = (x, ocg):
// each LDS x-read feeds 4 v_fma_f64. Tap order (ky,kx) identical to R1;
// out-of-range taps contribute fma(w,0,acc)=acc exactly -> bit-identical.
// ---------------------------------------------------------------------------
__global__ __launch_bounds__(224) void conv1_lds(
    const float* __restrict__ x, const float* __restrict__ w,
    const float* __restrict__ b, u16* __restrict__ out) {
  __shared__ float xt[3][30][18];
  __shared__ double wl[32][9];

  int blk = blockIdx.x;
  int y = blk % 28, n = blk / 28;
  int tid = threadIdx.x;

  for (int i = tid; i < 288; i += 224) wl[i / 9][i % 9] = (double)w[i];
  for (int i = tid; i < 3 * 30 * 16; i += 224) {
    int r = i / 480; int rem = i % 480;
    int col = rem / 16; int t = rem % 16;
    int yi = y - 1 + r, xi = col - 1;
    float v = 0.0f;
    if ((unsigned)yi < 28u && (unsigned)xi < 28u)
      v = x[((size_t)(n * 28 + yi) * 28 + xi) * 16 + t];
    xt[r][col][t] = v;
  }
  __syncthreads();

  int xx = tid % 28, ocg = tid / 28, oc0 = ocg * 4;

  double acc[4][TT];
#pragma unroll
  for (int j = 0; j < 4; ++j) {
    double bv = (double)b[oc0 + j];
#pragma unroll
    for (int t = 0; t < TT; ++t) acc[j][t] = bv;
  }

#pragma unroll
  for (int ky = 0; ky < 3; ++ky)
#pragma unroll
    for (int kx = 0; kx < 3; ++kx) {
      int ko = ky * 3 + kx;
      double w0 = wl[oc0][ko], w1 = wl[oc0 + 1][ko];
      double w2 = wl[oc0 + 2][ko], w3 = wl[oc0 + 3][ko];
#pragma unroll
      for (int t = 0; t < TT; ++t) {
        double xv = (double)xt[ky][xx + kx][t];
        acc[0][t] = fma(w0, xv, acc[0][t]);
        acc[1][t] = fma(w1, xv, acc[1][t]);
        acc[2][t] = fma(w2, xv, acc[2][t]);
        acc[3][t] = fma(w3, xv, acc[3][t]);
      }
    }

#pragma unroll
  for (int j = 0; j < 4; ++j) {
    u32 mo = scan_spike(acc[j]);
    out[((size_t)(n * 32 + oc0 + j) * 28 + y) * 28 + xx] = (u16)mo;
  }
}

// ---------------------------------------------------------------------------
// Digit prep in MFMA B-frag order for the 3x3 convs (R4-verbatim, proven).
// ---------------------------------------------------------------------------
__global__ void prep_digits_frag(const float* __restrict__ w,
                                 signed char* __restrict__ Wd) {
  int tap = blockIdx.x;    // 9
  int lane = threadIdx.x;  // 64
  int oc = lane & 31, kh = lane >> 5;
  for (int j = 0; j < 16; ++j) {
    int c = kh * 16 + j;
    double xv = ldexp((double)w[((size_t)(oc * 32 + c)) * 9 + tap], 45);
    long long X = (long long)rint(xv);
    for (int p = 0; p < 6; ++p) {
      int d = (int)((X + 128) & 255) - 128;
      Wd[((size_t)((p * 9 + tap) * 64 + lane)) * 16 + j] = (signed char)d;
      X = (X - (long long)d) >> 8;
    }
  }
}

// ---------------------------------------------------------------------------
// Expand packed u16 masks -> T[nloc][30][30][16][32] bytes (R4-verbatim).
// ---------------------------------------------------------------------------
__global__ __launch_bounds__(256) void expand_masks(
    const u16* __restrict__ s, signed char* __restrict__ T, int nbase) {
  int site = blockIdx.x * 8 + (threadIdx.x >> 5);
  int gl = threadIdx.x & 31;
  int x = site % 28; int t1 = site / 28;
  int y = t1 % 28;   int nloc = t1 / 28;

  u32 v = (u32)s[(((size_t)(nbase + nloc) * 32 + gl) * 28 + y) * 28 + x];
  const u32 MK[5] = {0x0000FFFFu, 0x00FF00FFu, 0x0F0F0F0Fu,
                     0x33333333u, 0x55555555u};
#pragma unroll
  for (int i = 0; i < 5; ++i) {
    int sh = 16 >> i;
    u32 mk = MK[i];
    u32 p = (u32)__shfl_xor((int)v, sh);
    v = ((gl & sh) == 0) ? ((v & mk) | ((p & mk) << sh))
                         : ((v & ~mk) | ((p & ~mk) >> sh));
  }
  if (gl < 16) {
    u32 dw[8];
#pragma unroll
    for (int d = 0; d < 8; ++d) {
      u32 nib = (v >> (4 * d)) & 0xFu;
      dw[d] = (nib * 0x00204081u) & 0x01010101u;
    }
    signed char* Tp =
        T + (((size_t)nloc * 30 + y + 1) * 30 + (x + 1)) * 512 + gl * 32;
    *(i32x4*)Tp = (i32x4){(int)dw[0], (int)dw[1], (int)dw[2], (int)dw[3]};
    *(i32x4*)(Tp + 16) = (i32x4){(int)dw[4], (int)dw[5], (int)dw[6], (int)dw[7]};
  }
}

// ---------------------------------------------------------------------------
// Integer epilogue for 32x32 i8 MFMA C-layout (R4-verbatim, proven).
// ---------------------------------------------------------------------------
template <bool WRITE_T, bool HAS_RES>
__device__ __forceinline__ void epi_i8(long long (&cc)[16], int h, int oc,
                                       int px_out, int y, int nloc, int n_g,
                                       const float* bias,
                                       const u16* __restrict__ res,
                                       signed char* __restrict__ Tout,
                                       u16* __restrict__ mout) {
  long long recv[8];
#pragma unroll
  for (int j = 0; j < 8; ++j) {
    long long send = h ? cc[j] : cc[8 + j];
    recv[j] = shfl_xor64(send, 32);
  }
  long long B45 = (long long)rint((double)bias[oc] * 35184372088832.0);
  u32 rm = 0;
  if (HAS_RES && px_out < 28)
    rm = res[(((size_t)n_g * 32 + oc) * 28 + y) * 28 + px_out];
  long long u = 0;
  u32 mo = 0;
  const long long TH = 1LL << 45;
#pragma unroll
  for (int t = 0; t < TT; ++t) {
    int lo = (t & 3) + 4 * (t >> 3);
    int sel = (t >> 2) & 1;
    long long own = h ? cc[8 + lo] : cc[lo];
    long long ut = (sel ^ h) ? recv[lo] : own;
    ut += B45 + (((rm >> t) & 1u) ? TH : 0);
    u += ut;
    if (u >= TH) { mo |= (1u << t); u -= TH; }
  }
  if (px_out < 28) {
    if (WRITE_T) {
      signed char* Tp =
          Tout + (((size_t)nloc * 30 + y + 1) * 30 + px_out + 1) * 512 + oc;
#pragma unroll
      for (int t = 0; t < TT; ++t)
        Tp[t * 32] = (signed char)((mo >> t) & 1u);
    } else {
      mout[(((size_t)n_g * 32 + oc) * 28 + y) * 28 + px_out] = (u16)mo;
    }
  }
}

// ---------------------------------------------------------------------------
// conv3x3 32->32 via exact i8 32x32x32 MFMA (R4-verbatim, proven).
// ---------------------------------------------------------------------------
template <bool WRITE_T, bool HAS_RES>
__global__ __launch_bounds__(256, 2) void conv_i8(
    const signed char* __restrict__ Tin, const signed char* __restrict__ Wd,
    const float* __restrict__ bias, const u16* __restrict__ res,
    signed char* __restrict__ Tout, u16* __restrict__ mout, int nbase) {
  __shared__ signed char WL[6 * 9 * 1024];
  int tid = threadIdx.x;
  for (int j = tid; j < 3456; j += 256)
    ((i32x4*)WL)[j] = ((const i32x4*)Wd)[j];
  __syncthreads();

  int blk = blockIdx.x;
  int xblk = blk & 1; int b2 = blk >> 1;
  int y = b2 % 28;    int nloc = b2 / 28;
  int lane = tid & 63, wid = tid >> 6;
  int h = lane >> 5, rowlane = lane & 31;
  int pxr = rowlane >> 4, tA = rowlane & 15;
  int pxb = xblk * 16 + wid * 4;

  i32x4 A0[9], A1[9];
  const signed char* Tn = Tin + (size_t)nloc * (30 * 30 * 512);
#pragma unroll
  for (int ky = 0; ky < 3; ++ky)
#pragma unroll
    for (int kx = 0; kx < 3; ++kx) {
      int tap = ky * 3 + kx;
      int ypad = y + ky;
      int x0 = pxb + pxr + kx;     if (x0 > 29) x0 = 29;
      int x1 = pxb + 2 + pxr + kx; if (x1 > 29) x1 = 29;
      A0[tap] = *(const i32x4*)(Tn + ((size_t)(ypad * 30 + x0)) * 512 +
                                tA * 32 + h * 16);
      A1[tap] = *(const i32x4*)(Tn + ((size_t)(ypad * 30 + x1)) * 512 +
                                tA * 32 + h * 16);
    }

  long long c0[16], c1[16];
#pragma unroll
  for (int r = 0; r < 16; ++r) { c0[r] = 0; c1[r] = 0; }

#pragma unroll
  for (int p = 0; p < 6; ++p) {
    i32x16 a0 = {0, 0, 0, 0, 0, 0, 0, 0, 0, 0, 0, 0, 0, 0, 0, 0};
    i32x16 a1 = {0, 0, 0, 0, 0, 0, 0, 0, 0, 0, 0, 0, 0, 0, 0, 0};
#pragma unroll
    for (int tap = 0; tap < 9; ++tap) {
      i32x4 Bf = *(const i32x4*)&WL[((size_t)((p * 9 + tap) * 64 + lane)) * 16];
      a0 = __builtin_amdgcn_mfma_i32_32x32x32_i8(A0[tap], Bf, a0, 0, 0, 0);
      a1 = __builtin_amdgcn_mfma_i32_32x32x32_i8(A1[tap], Bf, a1, 0, 0, 0);
    }
#pragma unroll
    for (int r = 0; r < 16; ++r) {
      c0[r] += ((long long)a0[r]) << (8 * p);
      c1[r] += ((long long)a1[r]) << (8 * p);
    }
  }

  int n_g = nbase + nloc;
  int oc = rowlane;
  epi_i8<WRITE_T, HAS_RES>(c0, h, oc, pxb + h, y, nloc, n_g, bias, res, Tout,
                           mout);
  epi_i8<WRITE_T, HAS_RES>(c1, h, oc, pxb + 2 + h, y, nloc, n_g, bias, res,
                           Tout, mout);
}

// ---------------------------------------------------------------------------
// 2x2 average pool + spike (R3-verbatim).
// ---------------------------------------------------------------------------
__global__ __launch_bounds__(256) void pool_spike(
    const u16* __restrict__ in, u16* __restrict__ out) {
  int idx = blockIdx.x * 256 + threadIdx.x;
  const int total = 128 * 32 * 14 * 14;
  if (idx >= total) return;
  int xx = idx % 14; int t1 = idx / 14;
  int yy = t1 % 14;  int t2 = t1 / 14;
  int c  = t2 % 32;  int n  = t2 / 32;

  const u16* base = in + ((size_t)(n * 32 + c) * 28 + yy * 2) * 28 + xx * 2;
  u32 m00 = base[0], m01 = base[1], m10 = base[28], m11 = base[29];

  double acc[TT];
#pragma unroll
  for (int t = 0; t < TT; ++t) {
    u32 s = ((m00 >> t) & 1u) + ((m01 >> t) & 1u) + ((m10 >> t) & 1u) +
            ((m11 >> t) & 1u);
    acc[t] = 0.25 * (double)s;
  }
  out[idx] = (u16)scan_spike(acc);
}

// ---------------------------------------------------------------------------
// conv1x1 on packed binary input + optional residual + spike (R3-verbatim).
// ---------------------------------------------------------------------------
template <int CIN>
__global__ __launch_bounds__(256) void conv1x1_spike(
    const u16* __restrict__ in, const float* __restrict__ w,
    const float* __restrict__ b, const u16* __restrict__ res,
    u16* __restrict__ out, int N, int Cout, int HW) {
  int idx = blockIdx.x * 256 + threadIdx.x;
  int total = N * Cout * HW;
  if (idx >= total) return;
  int p = idx % HW; int t1 = idx / HW;
  int o = t1 % Cout; int n = t1 / Cout;

  double acc[TT];
  double bv = (double)b[o];
#pragma unroll
  for (int t = 0; t < TT; ++t) acc[t] = bv;

  const u16* inp = in + (size_t)n * CIN * HW + p;
  const float* wo = w + (size_t)o * CIN;
#pragma unroll 4
  for (int c = 0; c < CIN; ++c) {
    u32 m = inp[c * HW];
    double wh = 0.5 * (double)wo[c];
#pragma unroll
    for (int t = 0; t < TT; ++t) {
      u32 hi = (m << (30 - t)) & 0x40000000u;
      acc[t] = fma(wh, __hiloint2double((int)hi, 0), acc[t]);
    }
  }
  if (res) {
    u32 m = res[idx];
#pragma unroll
    for (int t = 0; t < TT; ++t) acc[t] += ((m >> t) & 1u) ? 1.0 : 0.0;
  }
  out[idx] = (u16)scan_spike(acc);
}

// ---------------------------------------------------------------------------
// f64 FMA conv3x3 (L6: 16ch 14x14, small) (R3-verbatim).
// ---------------------------------------------------------------------------
template <int CIN, int COUT, int H, int W>
__global__ __launch_bounds__((COUT / 4) * 64) void conv3x3_fma(
    const u16* __restrict__ in, const float* __restrict__ w,
    const float* __restrict__ b, const u16* __restrict__ res,
    u16* __restrict__ out) {
  constexpr int TX = 16, TY = 4;
  constexpr int TILESX = (W + TX - 1) / TX;
  constexpr int TILESY = (H + TY - 1) / TY;
  constexpr int HALO = 6 * (TX + 2);
  constexpr int BLOCK = (COUT / 4) * 64;
  __shared__ u16 lds[CIN][6][TX + 2];

  int blk = blockIdx.x;
  int tx = blk % TILESX; int t1 = blk / TILESX;
  int ty = t1 % TILESY;  int n  = t1 / TILESY;
  int x0 = tx * TX, y0 = ty * TY;

  int tid = threadIdx.x;

  const u16* inn = in + (size_t)n * CIN * H * W;
  for (int idx = tid; idx < CIN * HALO; idx += BLOCK) {
    int c = idx / HALO; int rem = idx % HALO;
    int r = rem / (TX + 2); int cc = rem % (TX + 2);
    int gy = y0 - 1 + r, gx = x0 - 1 + cc;
    u16 v = 0;
    if ((unsigned)gy < (unsigned)H && (unsigned)gx < (unsigned)W)
      v = inn[(size_t)c * H * W + gy * W + gx];
    lds[c][r][cc] = v;
  }
  __syncthreads();

  int lane = tid & 63;
  int og = __builtin_amdgcn_readfirstlane(tid >> 6);
  int oc0 = og * 4;
  int px = lane & 15, py = lane >> 4;

  double acc[4][TT];
#pragma unroll
  for (int j = 0; j < 4; ++j) {
    double bv = (double)b[oc0 + j];
#pragma unroll
    for (int t = 0; t < TT; ++t) acc[j][t] = bv;
  }

  for (int c = 0; c < CIN; ++c) {
    const float* wc = w + ((size_t)oc0 * CIN + c) * 9;
#pragma unroll
    for (int ky = 0; ky < 3; ++ky) {
#pragma unroll
      for (int kx = 0; kx < 3; ++kx) {
        u32 m = lds[c][py + ky][px + kx];
        int ko = ky * 3 + kx;
        double wh0 = 0.5 * (double)wc[ko];
        double wh1 = 0.5 * (double)wc[CIN * 9 + ko];
        double wh2 = 0.5 * (double)wc[2 * CIN * 9 + ko];
        double wh3 = 0.5 * (double)wc[3 * CIN * 9 + ko];
#pragma unroll
        for (int t = 0; t < TT; ++t) {
          u32 hi = (m << (30 - t)) & 0x40000000u;
          double bf = __hiloint2double((int)hi, 0);
          acc[0][t] = fma(wh0, bf, acc[0][t]);
          acc[1][t] = fma(wh1, bf, acc[1][t]);
          acc[2][t] = fma(wh2, bf, acc[2][t]);
          acc[3][t] = fma(wh3, bf, acc[3][t]);
        }
      }
    }
  }

  int gx = x0 + px, gy = y0 + py;
  if (gx < W && gy < H) {
#pragma unroll
    for (int j = 0; j < 4; ++j) {
      size_t oidx = ((size_t)(n * COUT + oc0 + j) * H + gy) * W + gx;
      double u = 0.0;
      u32 mo = 0;
      if (res) {
        u32 rm = res[oidx];
#pragma unroll
        for (int t = 0; t < TT; ++t) {
          double a = acc[j][t] + (((rm >> t) & 1u) ? 1.0 : 0.0);
          u += a;
          if (u >= 1.0) { mo |= (1u << t); u -= 1.0; }
        }
      } else {
#pragma unroll
        for (int t = 0; t < TT; ++t) {
          u += acc[j][t];
          if (u >= 1.0) { mo |= (1u << t); u -= 1.0; }
        }
      }
      out[oidx] = (u16)mo;
    }
  }
}

// ---------------------------------------------------------------------------
// Expand s7 masks -> T7[n][t][6272] bytes for dense1 A-operand. Same proven
// 32x32 bit-transpose as expand_masks; 32 contiguous f-bytes per (n,t).
// ---------------------------------------------------------------------------
__global__ __launch_bounds__(256) void expand_t7(
    const u16* __restrict__ s, signed char* __restrict__ T) {
  int site = blockIdx.x * 8 + (threadIdx.x >> 5);  // 128*196 sites
  int gl = threadIdx.x & 31;
  int fc = site % 196; int n = site / 196;

  u32 v = (u32)s[(size_t)n * 6272 + fc * 32 + gl];
  const u32 MK[5] = {0x0000FFFFu, 0x00FF00FFu, 0x0F0F0F0Fu,
                     0x33333333u, 0x55555555u};
#pragma unroll
  for (int i = 0; i < 5; ++i) {
    int sh = 16 >> i;
    u32 mk = MK[i];
    u32 p = (u32)__shfl_xor((int)v, sh);
    v = ((gl & sh) == 0) ? ((v & mk) | ((p & mk) << sh))
                         : ((v & ~mk) | ((p & ~mk) >> sh));
  }
  if (gl < 16) {
    u32 dw[8];
#pragma unroll
    for (int d = 0; d < 8; ++d) {
      u32 nib = (v >> (4 * d)) & 0xFu;
      dw[d] = (nib * 0x00204081u) & 0x01010101u;
    }
    signed char* Tp = T + ((size_t)n * 16 + gl) * 6272 + fc * 32;
    *(i32x4*)Tp = (i32x4){(int)dw[0], (int)dw[1], (int)dw[2], (int)dw[3]};
    *(i32x4*)(Tp + 16) = (i32x4){(int)dw[4], (int)dw[5], (int)dw[6], (int)dw[7]};
  }
}

// ---------------------------------------------------------------------------
// wf1 digit prep, B-frag order: Wd[((g*6+p)*196+kc)*1024 + lane*16 + j] =
// digit_p(wf1[o=g*32+(lane&31)][f=kc*32+(lane>>5)*16+j]). Thread per 16B
// output group (coalesced 16B writes). Digit via the +0x80.. byte trick
// (equivalent to R3's proven iterative extraction).
// ---------------------------------------------------------------------------
__global__ __launch_bounds__(256) void prep_dense_digits(
    const float* __restrict__ w, signed char* __restrict__ Wd) {
  int linear = blockIdx.x * 256 + threadIdx.x;  // < 301056
  int lane = linear & 63;
  int kc = (linear >> 6) % 196;
  int pg = (linear >> 6) / 196;  // = g*6 + p
  int p = pg % 6, g = pg / 6;
  int col = lane & 31, kh = lane >> 5;
  int o = g * 32 + col, fb = kc * 32 + kh * 16;

  alignas(16) signed char dig[16];
#pragma unroll
  for (int j = 0; j < 16; ++j) {
    double xv = (double)w[(size_t)o * 6272 + fb + j] * 35184372088832.0;
    long long X = (long long)rint(xv);
    unsigned long long Y = (unsigned long long)(X + 0x808080808080LL);
    dig[j] = (signed char)(int)(((Y >> (8 * p)) & 255u) - 128);
  }
  *(i32x4*)(Wd + (size_t)linear * 16) = *(const i32x4*)dig;
}

// ---------------------------------------------------------------------------
// Dense 6272->128 via exact i8 32x32x32 MFMA. Block = (ntile of 2 n, oc-group
// of 32); 4 waves K-split (49 chunks each), i64 LDS reduce, epi_i8-algebra
// epilogue (px<->nl isomorphism), integer LIF scan TH=2^45.
// ---------------------------------------------------------------------------
__global__ __launch_bounds__(256, 2) void dense1_i8(
    const signed char* __restrict__ T7, const signed char* __restrict__ Wd,
    const float* __restrict__ bias, u16* __restrict__ out) {
  __shared__ long long red[3][64][16];  // 24576 B
  int tid = threadIdx.x, lane = tid & 63, wid = tid >> 6;
  int bidx = blockIdx.x;
  int g = bidx & 3, n0 = (bidx >> 2) * 2;
  int nl = (lane >> 4) & 1, tA = lane & 15, kh = lane >> 5;

  const signed char* Arow =
      T7 + ((size_t)(n0 + nl) * 16 + tA) * 6272 + kh * 16;
  const signed char* Bbase = Wd + (size_t)g * 6 * 196 * 1024 + lane * 16;

  i32x16 acc[6];
#pragma unroll
  for (int p = 0; p < 6; ++p)
#pragma unroll
    for (int r = 0; r < 16; ++r) acc[p][r] = 0;

  int kc0 = wid * 49;
  for (int kc = kc0; kc < kc0 + 49; ++kc) {
    i32x4 Af = *(const i32x4*)(Arow + (size_t)kc * 32);
#pragma unroll
    for (int p = 0; p < 6; ++p) {
      i32x4 Bf = *(const i32x4*)(Bbase + (size_t)(p * 196 + kc) * 1024);
      acc[p] = __builtin_amdgcn_mfma_i32_32x32x32_i8(Af, Bf, acc[p], 0, 0, 0);
    }
  }

  long long cc[16];
#pragma unroll
  for (int r = 0; r < 16; ++r) {
    long long v = 0;
#pragma unroll
    for (int p = 0; p < 6; ++p) v += ((long long)acc[p][r]) << (8 * p);
    cc[r] = v;
  }

  if (wid) {
#pragma unroll
    for (int r = 0; r < 16; ++r) red[wid - 1][lane][r] = cc[r];
  }
  __syncthreads();
  if (wid == 0) {
#pragma unroll
    for (int w2 = 0; w2 < 3; ++w2)
#pragma unroll
      for (int r = 0; r < 16; ++r) cc[r] += red[w2][lane][r];

    int h = lane >> 5, col = lane & 31;
    long long recv[8];
#pragma unroll
    for (int j = 0; j < 8; ++j) {
      long long send = h ? cc[j] : cc[8 + j];
      recv[j] = shfl_xor64(send, 32);
    }
    long long B45 =
        (long long)rint((double)bias[g * 32 + col] * 35184372088832.0);
    long long u = 0;
    u32 mo = 0;
    const long long TH = 1LL << 45;
#pragma unroll
    for (int t = 0; t < TT; ++t) {
      int lo = (t & 3) + 4 * (t >> 3);
      int sel = (t >> 2) & 1;
      long long own = h ? cc[8 + lo] : cc[lo];
      long long ut = (sel ^ h) ? recv[lo] : own;
      ut += B45;
      u += ut;
      if (u >= TH) { mo |= (1u << t); u -= TH; }
    }
    out[(n0 + h) * 128 + g * 32 + col] = (u16)mo;
  }
}

// ---------------------------------------------------------------------------
// Dense 128 -> 10 + spike + rate (R3-verbatim).
// ---------------------------------------------------------------------------
__global__ __launch_bounds__(64) void dense2_out(
    const u16* __restrict__ in, const float* __restrict__ w,
    const float* __restrict__ b, float* __restrict__ out) {
  int idx = blockIdx.x * 64 + threadIdx.x;
  if (idx >= 1280) return;
  int o = idx % 10;
  int n = idx / 10;

  double acc[TT];
  double bv = (double)b[o];
#pragma unroll
  for (int t = 0; t < TT; ++t) acc[t] = bv;

  const u16* inn = in + (size_t)n * 128;
  const float* wo = w + (size_t)o * 128;
  for (int f = 0; f < 128; ++f) {
    u32 m = inn[f];
    double wv = (double)wo[f];
#pragma unroll
    for (int t = 0; t < TT; ++t) acc[t] += ((m >> t) & 1u) ? wv : 0.0;
  }
  u32 mo = scan_spike(acc);
  out[idx] = (float)__popc(mo) * 0.0625f;
}

// ---------------------------------------------------------------------------
extern "C" void kernel_launch(void* const* d_in, const int* in_sizes, int n_in,
                              void* d_out, int out_size, void* d_ws,
                              size_t ws_size, hipStream_t stream) {
  const float* x   = (const float*)d_in[0];
  const float* w1  = (const float*)d_in[1];
  const float* b1  = (const float*)d_in[2];
  const float* w2  = (const float*)d_in[3];
  const float* b2  = (const float*)d_in[4];
  const float* w3  = (const float*)d_in[5];
  const float* b3  = (const float*)d_in[6];
  const float* w4  = (const float*)d_in[7];
  const float* b4  = (const float*)d_in[8];
  const float* w5  = (const float*)d_in[9];
  const float* b5  = (const float*)d_in[10];
  const float* w6  = (const float*)d_in[11];
  const float* b6  = (const float*)d_in[12];
  const float* wf1 = (const float*)d_in[13];
  const float* bf1 = (const float*)d_in[14];
  const float* wf2 = (const float*)d_in[15];
  const float* bf2 = (const float*)d_in[16];
  float* out = (float*)d_out;

  // Workspace layout (byte offsets). ~47.3 MB total (same as R4).
  char* W = (char*)d_ws;
  u16* s1 = (u16*)(W + 0);               // [128,32,28,28]
  u16* s3 = (u16*)(W + 6422528);
  u16* s4 = (u16*)(W + 12845056);        // [128,32,14,14]
  u16* s5 = (u16*)(W + 14450688);        // [128,16,14,14]
  u16* s6 = (u16*)(W + 15253504);
  u16* s7 = (u16*)(W + 16056320);        // [128,32,14,14]
  u16* s8 = (u16*)(W + 17661952);        // [128,128]
  signed char* Wd2 = (signed char*)(W + 17694720);
  signed char* Wd3 = (signed char*)(W + 17750016);
  signed char* T1c = (signed char*)(W + 17805312);  // 14,745,600 B
  signed char* T2c = (signed char*)(W + 32550912);  // 14,745,600 B
  // dense1 buffers alias the T regions (free after the conv chunk loop):
  signed char* T7  = T1c;                            // 12,845,056 B
  signed char* Wd1 = T2c;                            //  4,816,896 B

  const size_t TSZ = (size_t)32 * 30 * 30 * 512;

  prep_digits_frag<<<9, 64, 0, stream>>>(w2, Wd2);
  prep_digits_frag<<<9, 64, 0, stream>>>(w3, Wd3);
  hipMemsetAsync(T1c, 0, TSZ, stream);
  hipMemsetAsync(T2c, 0, TSZ, stream);

  // L1: conv3x3 1->32 + spike (LDS-staged f64, 4 oc/thread)
  conv1_lds<<<3584, 224, 0, stream>>>(x, w1, b1, s1);

  // L2/L3 in 4 n-chunks of 32 (i8 MFMA)
  for (int k = 0; k < 4; ++k) {
    expand_masks<<<3136, 256, 0, stream>>>(s1, T1c, k * 32);
    conv_i8<true, false><<<1792, 256, 0, stream>>>(T1c, Wd2, b2, nullptr, T2c,
                                                   nullptr, k * 32);
    conv_i8<false, true><<<1792, 256, 0, stream>>>(T2c, Wd3, b3, s1, nullptr,
                                                   s3, k * 32);
  }

  // L4: avgpool2 + spike
  pool_spike<<<3136, 256, 0, stream>>>(s3, s4);
  // L5: conv1x1 32->16 + spike
  conv1x1_spike<32><<<1568, 256, 0, stream>>>(s4, w4, b4, nullptr, s5, 128, 16,
                                              196);
  // L6: conv3x3 16->16 + spike (f64)
  conv3x3_fma<16, 16, 14, 14><<<512, 256, 0, stream>>>(s5, w5, b5, nullptr, s6);
  // L7: conv1x1 16->32 + residual(s4) + spike
  conv1x1_spike<16><<<3136, 256, 0, stream>>>(s6, w6, b6, s4, s7, 128, 32, 196);

  // L8: dense 6272->128 + spike (i8 MFMA; T7/Wd1 reuse T1c/T2c)
  expand_t7<<<3136, 256, 0, stream>>>(s7, T7);
  prep_dense_digits<<<1176, 256, 0, stream>>>(wf1, Wd1);
  dense1_i8<<<256, 256, 0, stream>>>(T7, Wd1, bf1, s8);

  // L9: dense 128->10 + spike + rate
  dense2_out<<<20, 64, 0, stream>>>(s8, wf2, bf2, out);
}